// Round 1
// baseline (3747.042 us; speedup 1.0000x reference)
//
#include <hip/hip_runtime.h>
#include <hip/hip_bf16.h>
#include <math.h>

// Problem constants
#define BB 16
#define NN 500
#define QQ 25
#define CC 80
#define RR 3
#define DD 512
#define EE 3072
#define HOPS 5
#define MROWS (BB*NN)   // 8000

// ---------------------------------------------------------------------------
// Generic 64x64x16 fp32 tiled GEMM, 256 threads, 4x4 microtile per thread.
// MODE 0: C = A@W + bias                        (query GEMM, M=400,K=3072,N=512)
// MODE 1: nc = tanh(A@W+bias); C2 = nc*nmask    (nodes GEMM, M=8000,K=3072)
// MODE 2: C = (A@W+bias)*nmask                  (h GEMM, M=8000,K=512)
// MODE 3: batched: C[z] = A[z]@W[z] + E1[z]     (update = adjsum@h + h, M=500,K=500)
// MODE 4: gate: acc over K=1024 of [A|A2]@W; att=sig(acc+b)*nmask;
//         C = att*tanh(A[m,col]) + (1-att)*A2[m,col]    (A=update, A2=last)
// MODE 5: final: A-tile generated from segments [nc, n2q, nc*n2q, nc*q2n];
//         C = tanh(acc + bias)                  (M=8000,K=2048,N=128)
// ---------------------------------------------------------------------------
template<int MODE>
__global__ __launch_bounds__(256)
void gemm64(const float* __restrict__ A, const float* __restrict__ A2,
            const float* __restrict__ W, const float* __restrict__ bias,
            const float* __restrict__ E1,
            float* __restrict__ C, float* __restrict__ C2,
            const int* __restrict__ nlen,
            int M, int K, int Ncols)
{
    __shared__ float As[16][68];
    __shared__ float Bs[16][68];

    const int t  = threadIdx.x;
    const int n0 = blockIdx.x * 64;
    const int m0 = blockIdx.y * 64;
    const int z  = blockIdx.z;

    const float* Ab = A;
    const float* Wb = W;
    const float* Eb = E1;
    float*       Cb = C;
    if constexpr (MODE == 3) {
        Ab = A  + (size_t)z * NN * NN;
        Wb = W  + (size_t)z * NN * DD;
        Eb = E1 + (size_t)z * NN * DD;
        Cb = C  + (size_t)z * NN * DD;
    }

    const int tx = t & 15, ty = t >> 4;
    const int a_m = t >> 4;   // 0..15
    const int a_k = t & 15;   // 0..15
    const int w_k = t >> 6;   // 0..3
    const int w_n = t & 63;   // 0..63

    float acc[4][4] = {};

    for (int k0 = 0; k0 < K; k0 += 16) {
        // --- load A tile (64 rows x 16 k) ---
        #pragma unroll
        for (int i = 0; i < 4; ++i) {
            int row = m0 + a_m + i * 16;
            int k   = k0 + a_k;
            float v = 0.f;
            if (row < M && k < K) {
                if constexpr (MODE == 4) {
                    v = (k < DD) ? A[(size_t)row * DD + k]
                                 : A2[(size_t)row * DD + (k - DD)];
                } else if constexpr (MODE == 5) {
                    int seg = k >> 9, off = k & 511;
                    float ncv = A[(size_t)row * DD + off];
                    if (seg == 0)      v = ncv;
                    else if (seg == 1) v = A2[(size_t)row * DD + off];
                    else if (seg == 2) v = ncv * A2[(size_t)row * DD + off];
                    else { int b = row / NN; v = ncv * E1[(size_t)b * DD + off]; }
                } else {
                    v = Ab[(size_t)row * K + k];
                }
            }
            As[a_k][a_m + i * 16] = v;
        }
        // --- load W tile (16 k x 64 n) ---
        #pragma unroll
        for (int p = 0; p < 4; ++p) {
            int k = k0 + w_k + p * 4;
            float v = 0.f;
            if (k < K) v = Wb[(size_t)k * Ncols + n0 + w_n];
            Bs[w_k + p * 4][w_n] = v;
        }
        __syncthreads();

        #pragma unroll
        for (int kk = 0; kk < 16; ++kk) {
            float4 a4 = *(const float4*)(&As[kk][ty * 4]);
            float4 b4 = *(const float4*)(&Bs[kk][tx * 4]);
            float av[4] = {a4.x, a4.y, a4.z, a4.w};
            float bv[4] = {b4.x, b4.y, b4.z, b4.w};
            #pragma unroll
            for (int i = 0; i < 4; ++i)
                #pragma unroll
                for (int j = 0; j < 4; ++j)
                    acc[i][j] += av[i] * bv[j];
        }
        __syncthreads();
    }

    // --- epilogue ---
    #pragma unroll
    for (int i = 0; i < 4; ++i) {
        int row = m0 + ty * 4 + i;
        if (row >= M) continue;
        float nm = 1.f;
        if constexpr (MODE == 1 || MODE == 2 || MODE == 4) {
            int b = row / NN, n = row - b * NN;
            nm = (n < nlen[b]) ? 1.f : 0.f;
        }
        #pragma unroll
        for (int j = 0; j < 4; ++j) {
            int col = n0 + tx * 4 + j;
            size_t idx = (size_t)row * Ncols + col;
            float v = acc[i][j];
            if constexpr (MODE == 0) {
                C[idx] = v + bias[col];
            } else if constexpr (MODE == 1) {
                float tv = tanhf(v + bias[col]);
                C[idx]  = tv;
                C2[idx] = tv * nm;
            } else if constexpr (MODE == 2) {
                C[idx] = (v + bias[col]) * nm;
            } else if constexpr (MODE == 3) {
                Cb[idx] = v + Eb[idx];
            } else if constexpr (MODE == 4) {
                float u  = A [(size_t)row * DD + col];
                float l  = A2[(size_t)row * DD + col];
                float att = nm / (1.f + expf(-(v + bias[col])));
                C[idx] = att * tanhf(u) + (1.f - att) * l;
            } else if constexpr (MODE == 5) {
                C[idx] = tanhf(v + bias[col]);
            }
        }
    }
}

// adjsum[b,n,m] = sum_r adj[b,r,n,m]
__global__ __launch_bounds__(256)
void adjsum_kernel(const float* __restrict__ adj, float* __restrict__ adjsum)
{
    int i = blockIdx.x * 256 + threadIdx.x;
    const int per_b = NN * NN;
    if (i >= BB * per_b) return;
    int b = i / per_b, nm = i - b * per_b;
    const float* base = adj + (size_t)b * RR * per_b + nm;
    adjsum[i] = base[0] + base[per_b] + base[2 * per_b];
}

// per (b,n): sim row over q, softmax -> n2q row; also simmax[b,n]
__global__ __launch_bounds__(64)
void sim_n2q_kernel(const float* __restrict__ last, const float* __restrict__ query,
                    const float* __restrict__ Wa, float* __restrict__ n2q,
                    float* __restrict__ simmax)
{
    int bn = blockIdx.x;           // 0..7999
    int b  = bn / NN;
    int lane = threadIdx.x;
    const float* lrow = last + (size_t)bn * DD;
    const float* qb   = query + (size_t)b * QQ * DD;

    float l[8], coef[8];
    float apart = 0.f;
    #pragma unroll
    for (int i = 0; i < 8; ++i) {
        int d = lane + i * 64;
        float lv = lrow[d];
        l[i] = lv;
        apart  += lv * Wa[d];
        coef[i] = Wa[DD + d] + lv * Wa[2 * DD + d];
    }
    #pragma unroll
    for (int o = 32; o >= 1; o >>= 1) apart += __shfl_xor(apart, o, 64);

    float s[QQ];
    float smax = -INFINITY;
    #pragma unroll
    for (int q = 0; q < QQ; ++q) {
        float part = 0.f;
        #pragma unroll
        for (int i = 0; i < 8; ++i)
            part += qb[(size_t)q * DD + lane + i * 64] * coef[i];
        #pragma unroll
        for (int o = 32; o >= 1; o >>= 1) part += __shfl_xor(part, o, 64);
        s[q] = apart + part;
        smax = fmaxf(smax, s[q]);
    }
    if (lane == 0) simmax[bn] = smax;

    float den = 0.f;
    #pragma unroll
    for (int q = 0; q < QQ; ++q) { s[q] = expf(s[q] - smax); den += s[q]; }
    float inv = 1.f / den;

    float accv[8] = {};
    #pragma unroll
    for (int q = 0; q < QQ; ++q) {
        float p = s[q] * inv;
        #pragma unroll
        for (int i = 0; i < 8; ++i)
            accv[i] += p * qb[(size_t)q * DD + lane + i * 64];
    }
    #pragma unroll
    for (int i = 0; i < 8; ++i)
        n2q[(size_t)bn * DD + lane + i * 64] = accv[i];
}

// per b: b_att = softmax(simmax[b,:]) over all N; q2n[b,d] = sum_n b_att*nc
__global__ __launch_bounds__(256)
void batt_q2n_kernel(const float* __restrict__ simmax, const float* __restrict__ nc,
                     float* __restrict__ q2n)
{
    __shared__ float p[NN];
    __shared__ float sred[4];
    int b = blockIdx.x, t = threadIdx.x;
    int wv = t >> 6, lane = t & 63;
    const float* sm = simmax + (size_t)b * NN;

    float m = -INFINITY;
    for (int n = t; n < NN; n += 256) m = fmaxf(m, sm[n]);
    #pragma unroll
    for (int o = 32; o >= 1; o >>= 1) m = fmaxf(m, __shfl_xor(m, o, 64));
    if (lane == 0) sred[wv] = m;
    __syncthreads();
    float M4 = fmaxf(fmaxf(sred[0], sred[1]), fmaxf(sred[2], sred[3]));

    float den = 0.f;
    for (int n = t; n < NN; n += 256) { float e = expf(sm[n] - M4); p[n] = e; den += e; }
    #pragma unroll
    for (int o = 32; o >= 1; o >>= 1) den += __shfl_xor(den, o, 64);
    __syncthreads();
    if (lane == 0) sred[wv] = den;
    __syncthreads();
    float DEN = sred[0] + sred[1] + sred[2] + sred[3];
    float invD = 1.f / DEN;

    for (int d = t; d < DD; d += 256) {
        float acc = 0.f;
        for (int n = 0; n < NN; ++n)
            acc += p[n] * nc[((size_t)b * NN + n) * DD + d];
        q2n[(size_t)b * DD + d] = acc * invD;
    }
}

// raw[m] = dot(hidden[m,:128], Wo2) + bo2
__global__ __launch_bounds__(256)
void raw_kernel(const float* __restrict__ hidden, const float* __restrict__ Wo2,
                const float* __restrict__ bo2, float* __restrict__ raw)
{
    int m = blockIdx.x * 4 + (threadIdx.x >> 6);
    int lane = threadIdx.x & 63;
    float v = hidden[(size_t)m * 128 + lane]      * Wo2[lane]
            + hidden[(size_t)m * 128 + 64 + lane] * Wo2[64 + lane];
    #pragma unroll
    for (int o = 32; o >= 1; o >>= 1) v += __shfl_xor(v, o, 64);
    if (lane == 0) raw[m] = v + bo2[0];
}

// out[b,c] = max_n ( mask*raw == 0 ? -inf : mask*raw )
__global__ __launch_bounds__(64)
void out_kernel(const int* __restrict__ mask, const float* __restrict__ raw,
                float* __restrict__ out)
{
    int bc = blockIdx.x;     // b*CC + c
    int b  = bc / CC;
    int lane = threadIdx.x;
    const int*   mrow = mask + (size_t)bc * NN;
    const float* rrow = raw  + (size_t)b * NN;
    float mx = -INFINITY;
    for (int n = lane; n < NN; n += 64) {
        float v = (float)mrow[n] * rrow[n];
        v = (v == 0.f) ? -INFINITY : v;
        mx = fmaxf(mx, v);
    }
    #pragma unroll
    for (int o = 32; o >= 1; o >>= 1) mx = fmaxf(mx, __shfl_xor(mx, o, 64));
    if (lane == 0) out[bc] = mx;
}

extern "C" void kernel_launch(void* const* d_in, const int* in_sizes, int n_in,
                              void* d_out, int out_size, void* d_ws, size_t ws_size,
                              hipStream_t stream)
{
    const float* nodes_elmo = (const float*)d_in[0];   // (B,N,3,1024) -> (8000,3072)
    const float* query_elmo = (const float*)d_in[1];   // (B,Q,3,1024) -> (400,3072)
    const float* adj        = (const float*)d_in[2];   // (B,R,N,N)
    const int*   mask       = (const int*)  d_in[3];   // (B,C,N)
    const int*   nlen       = (const int*)  d_in[4];   // (B,)
    const float* Wq  = (const float*)d_in[6];
    const float* bq  = (const float*)d_in[7];
    const float* Wn  = (const float*)d_in[8];
    const float* bn  = (const float*)d_in[9];
    const float* Wh  = (const float*)d_in[10];
    const float* bh  = (const float*)d_in[11];
    const float* Wc  = (const float*)d_in[12];
    const float* bc  = (const float*)d_in[13];
    const float* Wa  = (const float*)d_in[14];
    const float* Wo1 = (const float*)d_in[15];
    const float* bo1 = (const float*)d_in[16];
    const float* Wo2 = (const float*)d_in[17];
    const float* bo2 = (const float*)d_in[18];
    float* out = (float*)d_out;

    float* ws = (float*)d_ws;
    float* query   = ws;  ws += (size_t)BB * QQ * DD;     // 204800
    float* nc      = ws;  ws += (size_t)MROWS * DD;       // 4.1M
    float* last0   = ws;  ws += (size_t)MROWS * DD;
    float* last1   = ws;  ws += (size_t)MROWS * DD;
    float* hbuf    = ws;  ws += (size_t)MROWS * DD;
    float* update  = ws;  ws += (size_t)MROWS * DD;
    float* adjsum  = ws;  ws += (size_t)BB * NN * NN;     // 4.0M
    float* n2q     = ws;  ws += (size_t)MROWS * DD;
    float* simmax  = ws;  ws += MROWS;
    float* q2n     = ws;  ws += BB * DD;
    float* hidden  = ws;  ws += (size_t)MROWS * 128;
    float* raw     = ws;  ws += MROWS;

    dim3 blk(256);

    // adjsum
    adjsum_kernel<<<(BB * NN * NN + 255) / 256, blk, 0, stream>>>(adj, adjsum);

    // query = query_elmo @ Wq + bq
    gemm64<0><<<dim3(DD / 64, (BB * QQ + 63) / 64, 1), blk, 0, stream>>>(
        query_elmo, nullptr, Wq, bq, nullptr, query, nullptr, nullptr,
        BB * QQ, EE, DD);

    // nc = tanh(nodes @ Wn + bn); last0 = nc * nmask
    gemm64<1><<<dim3(DD / 64, MROWS / 64, 1), blk, 0, stream>>>(
        nodes_elmo, nullptr, Wn, bn, nullptr, nc, last0, nlen,
        MROWS, EE, DD);

    float* lastCur = last0;
    float* lastNxt = last1;
    for (int hop = 0; hop < HOPS; ++hop) {
        // h = (last @ Wh + bh) * nmask
        gemm64<2><<<dim3(DD / 64, MROWS / 64, 1), blk, 0, stream>>>(
            lastCur, nullptr, Wh, bh, nullptr, hbuf, nullptr, nlen,
            MROWS, DD, DD);
        // update = adjsum @ h + h   (batched over b)
        gemm64<3><<<dim3(DD / 64, (NN + 63) / 64, BB), blk, 0, stream>>>(
            adjsum, nullptr, hbuf, nullptr, hbuf, update, nullptr, nullptr,
            NN, NN, DD);
        // gate: lastNxt = att*tanh(update) + (1-att)*lastCur
        gemm64<4><<<dim3(DD / 64, MROWS / 64, 1), blk, 0, stream>>>(
            update, lastCur, Wc, bc, nullptr, lastNxt, nullptr, nlen,
            MROWS, 2 * DD, DD);
        float* tmp = lastCur; lastCur = lastNxt; lastNxt = tmp;
    }

    // sim + row softmax + n2q + simmax
    sim_n2q_kernel<<<MROWS, dim3(64), 0, stream>>>(lastCur, query, Wa, n2q, simmax);

    // b_att softmax over n + q2n
    batt_q2n_kernel<<<BB, blk, 0, stream>>>(simmax, nc, q2n);

    // hidden = tanh(g @ Wo1 + bo1), g generated on the fly
    gemm64<5><<<dim3(128 / 64, MROWS / 64, 1), blk, 0, stream>>>(
        nc, n2q, Wo1, bo1, q2n, hidden, nullptr, nullptr,
        MROWS, 4 * DD, 128);

    // raw = hidden @ Wo2 + bo2
    raw_kernel<<<MROWS / 4, blk, 0, stream>>>(hidden, Wo2, bo2, raw);

    // masked max output
    out_kernel<<<BB * CC, dim3(64), 0, stream>>>(mask, raw, out);
}

// Round 2
// 1591.996 us; speedup vs baseline: 2.3537x; 2.3537x over previous
//
#include <hip/hip_runtime.h>
#include <hip/hip_bf16.h>
#include <math.h>

// Problem constants
#define BB 16
#define NN 500
#define QQ 25
#define CC 80
#define RR 3
#define DD 512
#define EE 3072
#define HOPS 5
#define MROWS (BB*NN)   // 8000

typedef float f32x4  __attribute__((ext_vector_type(4)));
typedef short s16x8  __attribute__((ext_vector_type(8)));

static __device__ __forceinline__ short f2bf(float x) {
    __hip_bfloat16 h = __float2bfloat16(x);
    return __builtin_bit_cast(short, h);
}
static __device__ __forceinline__ float bf2f(short s) {
    __hip_bfloat16 h = __builtin_bit_cast(__hip_bfloat16, s);
    return __bfloat162float(h);
}

// ---------------------------------------------------------------------------
// MFMA GEMM: 128x128 tile, BK=64, 256 threads = 4 waves (2x2), 64x64 per wave.
// LDS layout per operand: [128 rows][64 k] bf16, 16B chunks XOR-swizzled:
//   byte(row, slot) = row*128 + ((slot ^ (row&7)) << 4), slot = k>>3.
// Both operands k-major (weights pre-transposed to [N][K]).
// MODE 0: C = A@W + bias            A=query_elmo fp32 (cvt in staging)
// MODE 1: nc=tanh(A@W+b); last=nc*nmask (both fp32+bf16)  A=nodes fp32
// MODE 2: h = (A@W+b)*nmask  -> bf16                      A=last bf16
// MODE 3: update[z] = adjsum[z]@hT[z] + h  -> bf16 (batched z)
// MODE 4: gate: att=sig([u|l]@Wc+b)*nm; out=att*tanh(u)+(1-att)*l (fp32+bf16)
// MODE 5: hidden = tanh(g@Wo1+b), g segments generated from bf16 nc/n2q/q2n
// ---------------------------------------------------------------------------
template<int MODE>
__global__ __launch_bounds__(256)
void gemm_mfma(const float* __restrict__ Af,
               const short* __restrict__ Ab, const short* __restrict__ Ab2,
               const short* __restrict__ Bt, const float* __restrict__ bias,
               float* __restrict__ Cf, short* __restrict__ Cb,
               float* __restrict__ Cf2, short* __restrict__ Cb2,
               const short* __restrict__ hadd, const float* __restrict__ lastf,
               const short* __restrict__ n2qb, const short* __restrict__ q2nb,
               const int* __restrict__ nlen,
               int M, int K, int N, int mclamp)
{
    __shared__ short Als[128 * 64];
    __shared__ short Bls[128 * 64];

    const int t    = threadIdx.x;
    const int lane = t & 63;
    const int w    = t >> 6;
    const int wm   = w >> 1;
    const int wn   = w & 1;
    const int n0   = blockIdx.x * 128;
    const int m0   = blockIdx.y * 128;
    const int z    = blockIdx.z;

    const size_t za = (MODE == 3) ? (size_t)z * (512 * 512) : 0;

    f32x4 acc[4][4];
    #pragma unroll
    for (int i = 0; i < 4; ++i)
        #pragma unroll
        for (int j = 0; j < 4; ++j)
            acc[i][j] = (f32x4){0.f, 0.f, 0.f, 0.f};

    for (int k0 = 0; k0 < K; k0 += 64) {
        // ---- stage A (4 chunks of 16B per thread) ----
        #pragma unroll
        for (int c = 0; c < 4; ++c) {
            int f = c * 256 + t;
            int row = f >> 3, slot = f & 7;
            int k = k0 + slot * 8;
            int rg = m0 + row; if (rg > mclamp) rg = mclamp;
            s16x8 v;
            if constexpr (MODE == 0 || MODE == 1) {
                const float* s = Af + (size_t)rg * K + k;
                #pragma unroll
                for (int j = 0; j < 8; ++j) v[j] = f2bf(s[j]);
            } else if constexpr (MODE == 2) {
                v = *(const s16x8*)(Ab + (size_t)rg * 512 + k);
            } else if constexpr (MODE == 3) {
                v = *(const s16x8*)(Ab + za + (size_t)rg * 512 + k);
            } else if constexpr (MODE == 4) {
                v = (k < 512) ? *(const s16x8*)(Ab  + (size_t)rg * 512 + k)
                              : *(const s16x8*)(Ab2 + (size_t)rg * 512 + (k - 512));
            } else { // MODE 5: g = [nc, n2q, nc*n2q, nc*q2n]
                int seg = k >> 9, off = k & 511;
                s16x8 a = *(const s16x8*)(Ab + (size_t)rg * 512 + off);
                if (seg == 0) v = a;
                else if (seg == 1) v = *(const s16x8*)(n2qb + (size_t)rg * 512 + off);
                else {
                    int b = rg / NN;
                    s16x8 o = (seg == 2) ? *(const s16x8*)(n2qb + (size_t)rg * 512 + off)
                                         : *(const s16x8*)(q2nb + (size_t)b * 512 + off);
                    #pragma unroll
                    for (int j = 0; j < 8; ++j) v[j] = f2bf(bf2f(a[j]) * bf2f(o[j]));
                }
            }
            *(s16x8*)&Als[row * 64 + ((slot ^ (row & 7)) << 3)] = v;
        }
        // ---- stage B ----
        #pragma unroll
        for (int c = 0; c < 4; ++c) {
            int f = c * 256 + t;
            int row = f >> 3, slot = f & 7;
            int k = k0 + slot * 8;
            s16x8 v = *(const s16x8*)(Bt + za + (size_t)(n0 + row) * K + k);
            *(s16x8*)&Bls[row * 64 + ((slot ^ (row & 7)) << 3)] = v;
        }
        __syncthreads();

        // ---- MFMA over the two K=32 halves ----
        #pragma unroll
        for (int ks = 0; ks < 2; ++ks) {
            s16x8 af[4], bf_[4];
            int s = ks * 4 + (lane >> 4);
            #pragma unroll
            for (int i = 0; i < 4; ++i) {
                int ar = wm * 64 + i * 16 + (lane & 15);
                af[i]  = *(const s16x8*)&Als[ar * 64 + ((s ^ (ar & 7)) << 3)];
                int br = wn * 64 + i * 16 + (lane & 15);
                bf_[i] = *(const s16x8*)&Bls[br * 64 + ((s ^ (br & 7)) << 3)];
            }
            #pragma unroll
            for (int i = 0; i < 4; ++i)
                #pragma unroll
                for (int j = 0; j < 4; ++j)
                    acc[i][j] = __builtin_amdgcn_mfma_f32_16x16x32_bf16(
                        af[i], bf_[j], acc[i][j], 0, 0, 0);
        }
        __syncthreads();
    }

    // ---- epilogue: C/D map col=lane&15, row=(lane>>4)*4+r ----
    #pragma unroll
    for (int mi = 0; mi < 4; ++mi) {
        #pragma unroll
        for (int ni = 0; ni < 4; ++ni) {
            f32x4 v = acc[mi][ni];
            int col   = n0 + wn * 64 + ni * 16 + (lane & 15);
            int rbase = m0 + wm * 64 + mi * 16 + ((lane >> 4) << 2);
            #pragma unroll
            for (int r = 0; r < 4; ++r) {
                int row = rbase + r;
                float x = v[r];
                if constexpr (MODE == 0) {
                    if (row < 400) Cf[(size_t)row * 512 + col] = x + bias[col];
                } else if constexpr (MODE == 1) {
                    if (row < MROWS) {
                        int b = row / NN, n = row - b * NN;
                        float nm = (n < nlen[b]) ? 1.f : 0.f;
                        float tv = tanhf(x + bias[col]);
                        size_t idx = (size_t)row * 512 + col;
                        Cf[idx]  = tv;       Cb[idx]  = f2bf(tv);
                        float lm = tv * nm;
                        Cf2[idx] = lm;       Cb2[idx] = f2bf(lm);
                    }
                } else if constexpr (MODE == 2) {
                    if (row < MROWS) {
                        int b = row / NN, n = row - b * NN;
                        float nm = (n < nlen[b]) ? 1.f : 0.f;
                        Cb[(size_t)row * 512 + col] = f2bf((x + bias[col]) * nm);
                    }
                } else if constexpr (MODE == 3) {
                    if (row < NN) {
                        size_t idx = ((size_t)z * NN + row) * 512 + col;
                        Cb[idx] = f2bf(x + bf2f(hadd[idx]));
                    }
                } else if constexpr (MODE == 4) {
                    if (row < MROWS) {
                        int b = row / NN, n = row - b * NN;
                        float nm = (n < nlen[b]) ? 1.f : 0.f;
                        size_t idx = (size_t)row * 512 + col;
                        float att = nm / (1.f + expf(-(x + bias[col])));
                        float u = bf2f(Ab[idx]);
                        float l = lastf[idx];
                        float o = att * tanhf(u) + (1.f - att) * l;
                        Cf[idx] = o;  Cb[idx] = f2bf(o);
                    }
                } else { // MODE 5
                    if (row < MROWS) Cf[(size_t)row * 128 + col] = tanhf(x + bias[col]);
                }
            }
        }
    }
}

// W [K][N] fp32 -> WT [N][K] bf16 (k-major for MFMA B operand)
__global__ __launch_bounds__(256)
void wtrans(const float* __restrict__ W, short* __restrict__ WT, int K, int N)
{
    __shared__ float tile[32][33];
    int n0 = blockIdx.x * 32, k0 = blockIdx.y * 32;
    int tx = threadIdx.x, ty = threadIdx.y;
    for (int i = ty; i < 32; i += 8)
        tile[i][tx] = W[(size_t)(k0 + i) * N + n0 + tx];
    __syncthreads();
    for (int i = ty; i < 32; i += 8)
        WT[(size_t)(n0 + i) * K + k0 + tx] = f2bf(tile[tx][i]);
}

// adjsum bf16 [16][512][512], zero-padded outside 500x500 (bf16 exact: 0..3)
__global__ __launch_bounds__(256)
void adjsum_conv(const float* __restrict__ adj, short* __restrict__ out)
{
    int i = blockIdx.x * 256 + threadIdx.x;
    int b = i >> 18;
    int rem = i & (512 * 512 - 1);
    int n = rem >> 9, m = rem & 511;
    float v = 0.f;
    if (n < NN && m < NN) {
        const float* base = adj + (((size_t)b * RR) * NN + n) * NN + m;
        v = base[0] + base[(size_t)NN * NN] + base[2 * (size_t)NN * NN];
    }
    out[i] = f2bf(v);
}

// h bf16 [8000][512] -> hT bf16 [16][512 d][512 m] (m>=500 zero)
__global__ __launch_bounds__(256)
void htrans(const short* __restrict__ h, short* __restrict__ hT)
{
    __shared__ float tile[32][33];
    int b = blockIdx.z;
    int m0 = blockIdx.y * 32, d0 = blockIdx.x * 32;
    int tx = threadIdx.x, ty = threadIdx.y;
    for (int i = ty; i < 32; i += 8) {
        int m = m0 + i;
        float v = 0.f;
        if (m < NN) v = bf2f(h[((size_t)b * NN + m) * 512 + d0 + tx]);
        tile[i][tx] = v;
    }
    __syncthreads();
    for (int i = ty; i < 32; i += 8)
        hT[((size_t)b * 512 + d0 + i) * 512 + m0 + tx] = f2bf(tile[tx][i]);
}

// per (b,n): sim row over q, softmax -> n2q (bf16); also simmax[b,n]
__global__ __launch_bounds__(64)
void sim_n2q_kernel(const float* __restrict__ last, const float* __restrict__ query,
                    const float* __restrict__ Wa, short* __restrict__ n2qb,
                    float* __restrict__ simmax)
{
    int bn = blockIdx.x;
    int b  = bn / NN;
    int lane = threadIdx.x;
    const float* lrow = last + (size_t)bn * DD;
    const float* qb   = query + (size_t)b * QQ * DD;

    float coef[8];
    float apart = 0.f;
    #pragma unroll
    for (int i = 0; i < 8; ++i) {
        int d = lane + i * 64;
        float lv = lrow[d];
        apart  += lv * Wa[d];
        coef[i] = Wa[DD + d] + lv * Wa[2 * DD + d];
    }
    #pragma unroll
    for (int o = 32; o >= 1; o >>= 1) apart += __shfl_xor(apart, o, 64);

    float s[QQ];
    float smax = -INFINITY;
    #pragma unroll
    for (int q = 0; q < QQ; ++q) {
        float part = 0.f;
        #pragma unroll
        for (int i = 0; i < 8; ++i)
            part += qb[(size_t)q * DD + lane + i * 64] * coef[i];
        #pragma unroll
        for (int o = 32; o >= 1; o >>= 1) part += __shfl_xor(part, o, 64);
        s[q] = apart + part;
        smax = fmaxf(smax, s[q]);
    }
    if (lane == 0) simmax[bn] = smax;

    float den = 0.f;
    #pragma unroll
    for (int q = 0; q < QQ; ++q) { s[q] = expf(s[q] - smax); den += s[q]; }
    float inv = 1.f / den;

    float accv[8] = {};
    #pragma unroll
    for (int q = 0; q < QQ; ++q) {
        float p = s[q] * inv;
        #pragma unroll
        for (int i = 0; i < 8; ++i)
            accv[i] += p * qb[(size_t)q * DD + lane + i * 64];
    }
    #pragma unroll
    for (int i = 0; i < 8; ++i)
        n2qb[(size_t)bn * DD + lane + i * 64] = f2bf(accv[i]);
}

// per b: b_att = softmax(simmax[b,:]); q2n[b,d] = sum_n b_att*nc  (bf16 out)
__global__ __launch_bounds__(256)
void batt_q2n_kernel(const float* __restrict__ simmax, const float* __restrict__ nc,
                     short* __restrict__ q2nb)
{
    __shared__ float p[NN];
    __shared__ float sred[4];
    int b = blockIdx.x, t = threadIdx.x;
    int wv = t >> 6, lane = t & 63;
    const float* sm = simmax + (size_t)b * NN;

    float m = -INFINITY;
    for (int n = t; n < NN; n += 256) m = fmaxf(m, sm[n]);
    #pragma unroll
    for (int o = 32; o >= 1; o >>= 1) m = fmaxf(m, __shfl_xor(m, o, 64));
    if (lane == 0) sred[wv] = m;
    __syncthreads();
    float M4 = fmaxf(fmaxf(sred[0], sred[1]), fmaxf(sred[2], sred[3]));

    float den = 0.f;
    for (int n = t; n < NN; n += 256) { float e = expf(sm[n] - M4); p[n] = e; den += e; }
    #pragma unroll
    for (int o = 32; o >= 1; o >>= 1) den += __shfl_xor(den, o, 64);
    __syncthreads();
    if (lane == 0) sred[wv] = den;
    __syncthreads();
    float DEN = sred[0] + sred[1] + sred[2] + sred[3];
    float invD = 1.f / DEN;

    for (int d = t; d < DD; d += 256) {
        float acc = 0.f;
        for (int n = 0; n < NN; ++n)
            acc += p[n] * nc[((size_t)b * NN + n) * DD + d];
        q2nb[(size_t)b * DD + d] = f2bf(acc * invD);
    }
}

// raw[m] = dot(hidden[m,:128], Wo2) + bo2
__global__ __launch_bounds__(256)
void raw_kernel(const float* __restrict__ hidden, const float* __restrict__ Wo2,
                const float* __restrict__ bo2, float* __restrict__ raw)
{
    int m = blockIdx.x * 4 + (threadIdx.x >> 6);
    int lane = threadIdx.x & 63;
    float v = hidden[(size_t)m * 128 + lane]      * Wo2[lane]
            + hidden[(size_t)m * 128 + 64 + lane] * Wo2[64 + lane];
    #pragma unroll
    for (int o = 32; o >= 1; o >>= 1) v += __shfl_xor(v, o, 64);
    if (lane == 0) raw[m] = v + bo2[0];
}

__global__ __launch_bounds__(64)
void out_kernel(const int* __restrict__ mask, const float* __restrict__ raw,
                float* __restrict__ out)
{
    int bc = blockIdx.x;
    int b  = bc / CC;
    int lane = threadIdx.x;
    const int*   mrow = mask + (size_t)bc * NN;
    const float* rrow = raw  + (size_t)b * NN;
    float mx = -INFINITY;
    for (int n = lane; n < NN; n += 64) {
        float v = (float)mrow[n] * rrow[n];
        v = (v == 0.f) ? -INFINITY : v;
        mx = fmaxf(mx, v);
    }
    #pragma unroll
    for (int o = 32; o >= 1; o >>= 1) mx = fmaxf(mx, __shfl_xor(mx, o, 64));
    if (lane == 0) out[bc] = mx;
}

extern "C" void kernel_launch(void* const* d_in, const int* in_sizes, int n_in,
                              void* d_out, int out_size, void* d_ws, size_t ws_size,
                              hipStream_t stream)
{
    const float* nodes_elmo = (const float*)d_in[0];
    const float* query_elmo = (const float*)d_in[1];
    const float* adj        = (const float*)d_in[2];
    const int*   mask       = (const int*)  d_in[3];
    const int*   nlen       = (const int*)  d_in[4];
    const float* Wq  = (const float*)d_in[6];
    const float* bq  = (const float*)d_in[7];
    const float* Wn  = (const float*)d_in[8];
    const float* bn  = (const float*)d_in[9];
    const float* Wh  = (const float*)d_in[10];
    const float* bh  = (const float*)d_in[11];
    const float* Wc  = (const float*)d_in[12];
    const float* bc  = (const float*)d_in[13];
    const float* Wa  = (const float*)d_in[14];
    const float* Wo1 = (const float*)d_in[15];
    const float* bo1 = (const float*)d_in[16];
    const float* Wo2 = (const float*)d_in[17];
    const float* bo2 = (const float*)d_in[18];
    float* out = (float*)d_out;

    char* p = (char*)d_ws;
    auto carveF = [&](size_t n) { float* r = (float*)p; p += n * 4; return r; };
    auto carveS = [&](size_t n) { short* r = (short*)p; p += n * 2; return r; };

    float* query_f   = carveF(400 * 512);
    float* nc_f      = carveF((size_t)MROWS * 512);
    float* last_f0   = carveF((size_t)MROWS * 512);
    float* last_f1   = carveF((size_t)MROWS * 512);
    float* hidden    = carveF((size_t)MROWS * 128);
    float* simmax    = carveF(MROWS);
    float* raw       = carveF(MROWS);
    short* nc_b      = carveS((size_t)MROWS * 512);
    short* last_b0   = carveS((size_t)MROWS * 512);
    short* last_b1   = carveS((size_t)MROWS * 512);
    short* h_b       = carveS((size_t)MROWS * 512);
    short* update_b  = carveS((size_t)MROWS * 512);
    short* n2q_b     = carveS((size_t)MROWS * 512);
    short* hT_b      = carveS((size_t)BB * 512 * 512);
    short* adjsum_b  = carveS((size_t)BB * 512 * 512);
    short* q2n_b     = carveS((size_t)BB * 512);
    short* WqT       = carveS((size_t)512 * 3072);
    short* WnT       = carveS((size_t)512 * 3072);
    short* WhT       = carveS((size_t)512 * 512);
    short* WcT       = carveS((size_t)512 * 1024);
    short* Wo1T      = carveS((size_t)128 * 2048);

    dim3 tb(32, 8);

    // weight transposes (fp32 -> k-major bf16)
    wtrans<<<dim3(16, 96), tb, 0, stream>>>(Wq,  WqT,  3072, 512);
    wtrans<<<dim3(16, 96), tb, 0, stream>>>(Wn,  WnT,  3072, 512);
    wtrans<<<dim3(16, 16), tb, 0, stream>>>(Wh,  WhT,  512,  512);
    wtrans<<<dim3(16, 32), tb, 0, stream>>>(Wc,  WcT,  1024, 512);
    wtrans<<<dim3(4,  64), tb, 0, stream>>>(Wo1, Wo1T, 2048, 128);

    adjsum_conv<<<(BB * 512 * 512) / 256, 256, 0, stream>>>(adj, adjsum_b);

    // query = query_elmo @ Wq + bq   (fp32 out)
    gemm_mfma<0><<<dim3(4, 4), 256, 0, stream>>>(
        query_elmo, nullptr, nullptr, WqT, bq,
        query_f, nullptr, nullptr, nullptr,
        nullptr, nullptr, nullptr, nullptr, nullptr, 400, 3072, 512, 399);

    // nc = tanh(nodes@Wn+bn); last0 = nc*nmask
    gemm_mfma<1><<<dim3(4, 63), 256, 0, stream>>>(
        nodes_elmo, nullptr, nullptr, WnT, bn,
        nc_f, nc_b, last_f0, last_b0,
        nullptr, nullptr, nullptr, nullptr, nlen, MROWS, 3072, 512, MROWS - 1);

    float* lf_cur = last_f0; float* lf_nxt = last_f1;
    short* lb_cur = last_b0; short* lb_nxt = last_b1;
    for (int hop = 0; hop < HOPS; ++hop) {
        gemm_mfma<2><<<dim3(4, 63), 256, 0, stream>>>(
            nullptr, lb_cur, nullptr, WhT, bh,
            nullptr, h_b, nullptr, nullptr,
            nullptr, nullptr, nullptr, nullptr, nlen, MROWS, 512, 512, MROWS - 1);

        htrans<<<dim3(16, 16, 16), tb, 0, stream>>>(h_b, hT_b);

        gemm_mfma<3><<<dim3(4, 4, 16), 256, 0, stream>>>(
            nullptr, adjsum_b, nullptr, hT_b, nullptr,
            nullptr, update_b, nullptr, nullptr,
            h_b, nullptr, nullptr, nullptr, nullptr, NN, 512, 512, 499);

        gemm_mfma<4><<<dim3(4, 63), 256, 0, stream>>>(
            nullptr, update_b, lb_cur, WcT, bc,
            lf_nxt, lb_nxt, nullptr, nullptr,
            nullptr, lf_cur, nullptr, nullptr, nlen, MROWS, 1024, 512, MROWS - 1);

        float* tf = lf_cur; lf_cur = lf_nxt; lf_nxt = tf;
        short* ts = lb_cur; lb_cur = lb_nxt; lb_nxt = ts;
    }

    sim_n2q_kernel<<<MROWS, 64, 0, stream>>>(lf_cur, query_f, Wa, n2q_b, simmax);
    batt_q2n_kernel<<<BB, 256, 0, stream>>>(simmax, nc_f, q2n_b);

    // hidden = tanh(g @ Wo1 + bo1)
    gemm_mfma<5><<<dim3(1, 63), 256, 0, stream>>>(
        nullptr, nc_b, nullptr, Wo1T, bo1,
        hidden, nullptr, nullptr, nullptr,
        nullptr, nullptr, n2q_b, q2n_b, nullptr, MROWS, 2048, 128, MROWS - 1);

    raw_kernel<<<MROWS / 4, 256, 0, stream>>>(hidden, Wo2, bo2, raw);
    out_kernel<<<BB * CC, 64, 0, stream>>>(mask, raw, out);
}

// Round 4
// 937.033 us; speedup vs baseline: 3.9988x; 1.6990x over previous
//
#include <hip/hip_runtime.h>
#include <hip/hip_bf16.h>
#include <math.h>

// Problem constants
#define BB 16
#define NN 500
#define QQ 25
#define CC 80
#define RR 3
#define DD 512
#define EE 3072
#define HOPS 5
#define MROWS (BB*NN)   // 8000

typedef float f32x4  __attribute__((ext_vector_type(4)));
typedef short s16x8  __attribute__((ext_vector_type(8)));
typedef short s16x4  __attribute__((ext_vector_type(4)));

static __device__ __forceinline__ short f2bf(float x) {
    __hip_bfloat16 h = __float2bfloat16(x);
    return __builtin_bit_cast(short, h);
}
static __device__ __forceinline__ float bf2f(short s) {
    __hip_bfloat16 h = __builtin_bit_cast(__hip_bfloat16, s);
    return __bfloat162float(h);
}

// fp32 -> bf16 bulk convert (n divisible by 8)
__global__ __launch_bounds__(256)
void cvt_bf16(const float* __restrict__ in, short* __restrict__ out, int n)
{
    int i = (blockIdx.x * 256 + threadIdx.x) * 8;
    if (i >= n) return;
    f32x4 a = *(const f32x4*)(in + i);
    f32x4 b = *(const f32x4*)(in + i + 4);
    s16x8 v;
    v[0]=f2bf(a[0]); v[1]=f2bf(a[1]); v[2]=f2bf(a[2]); v[3]=f2bf(a[3]);
    v[4]=f2bf(b[0]); v[5]=f2bf(b[1]); v[6]=f2bf(b[2]); v[7]=f2bf(b[3]);
    *(s16x8*)(out + i) = v;
}

// ---------------------------------------------------------------------------
// MFMA GEMM: 128x128 tile, BK=64, 256 threads = 4 waves (2x2), 64x64 per wave.
// All A/B operands bf16, k-major. XOR-swizzled LDS (16B chunk ^ row&7).
// MODE 0: query_b = A@W + bias (bf16 out)
// MODE 1: nc=tanh(A@W+b) -> nc_b; last = nc*nmask -> last_f (f32) + last_b
// MODE 2: h = (A@W+b)*nmask written TRANSPOSED -> hT[b][d][n] bf16
// MODE 3: update[z] = (adjsum+I)[z] @ hT[z]  -> bf16 row-major (batched z)
// MODE 4: gate: att=sig([u|l]@Wc+b)*nm; out=att*tanh(u)+(1-att)*l (f32+bf16)
// MODE 5: hidden=tanh(g@Wo1+b); raw[m]=hidden·Wo2+bo2 fused (g generated)
// ---------------------------------------------------------------------------
template<int MODE>
__global__ __launch_bounds__(256)
void gemm_mfma(const short* __restrict__ Ab, const short* __restrict__ Ab2,
               const short* __restrict__ Bt, const float* __restrict__ bias,
               float* __restrict__ Cf, short* __restrict__ Cb,
               short* __restrict__ Cb2, const float* __restrict__ lastf,
               const short* __restrict__ n2qb, const short* __restrict__ q2nb,
               const float* __restrict__ Wo2, const float* __restrict__ bo2,
               float* __restrict__ rawout,
               const int* __restrict__ nlen,
               int M, int K, int N, int mclamp)
{
    __shared__ short Als[128 * 64];
    __shared__ short Bls[128 * 64];
    __shared__ float rawp[128][2];

    const int t    = threadIdx.x;
    const int lane = t & 63;
    const int w    = t >> 6;
    const int wm   = w >> 1;
    const int wn   = w & 1;
    const int n0   = blockIdx.x * 128;
    const int m0   = blockIdx.y * 128;
    const int z    = blockIdx.z;

    const size_t za = (MODE == 3) ? (size_t)z * (512 * 512) : 0;

    f32x4 acc[4][4];
    #pragma unroll
    for (int i = 0; i < 4; ++i)
        #pragma unroll
        for (int j = 0; j < 4; ++j)
            acc[i][j] = (f32x4){0.f, 0.f, 0.f, 0.f};

    for (int k0 = 0; k0 < K; k0 += 64) {
        // ---- stage A ----
        #pragma unroll
        for (int c = 0; c < 4; ++c) {
            int f = c * 256 + t;
            int row = f >> 3, slot = f & 7;
            int k = k0 + slot * 8;
            int rg = m0 + row; if (rg > mclamp) rg = mclamp;
            s16x8 v;
            if constexpr (MODE == 4) {
                v = (k < 512) ? *(const s16x8*)(Ab  + (size_t)rg * 512 + k)
                              : *(const s16x8*)(Ab2 + (size_t)rg * 512 + (k - 512));
            } else if constexpr (MODE == 5) {
                int seg = k >> 9, off = k & 511;
                s16x8 a = *(const s16x8*)(Ab + (size_t)rg * 512 + off);
                if (seg == 0) v = a;
                else if (seg == 1) v = *(const s16x8*)(n2qb + (size_t)rg * 512 + off);
                else {
                    int b = rg / NN;
                    s16x8 o = (seg == 2) ? *(const s16x8*)(n2qb + (size_t)rg * 512 + off)
                                         : *(const s16x8*)(q2nb + (size_t)b * 512 + off);
                    #pragma unroll
                    for (int j = 0; j < 8; ++j) v[j] = f2bf(bf2f(a[j]) * bf2f(o[j]));
                }
            } else if constexpr (MODE == 3) {
                v = *(const s16x8*)(Ab + za + (size_t)rg * 512 + k);
            } else {
                v = *(const s16x8*)(Ab + (size_t)rg * K + k);
            }
            *(s16x8*)&Als[row * 64 + ((slot ^ (row & 7)) << 3)] = v;
        }
        // ---- stage B ----
        #pragma unroll
        for (int c = 0; c < 4; ++c) {
            int f = c * 256 + t;
            int row = f >> 3, slot = f & 7;
            int k = k0 + slot * 8;
            s16x8 v = *(const s16x8*)(Bt + za + (size_t)(n0 + row) * K + k);
            *(s16x8*)&Bls[row * 64 + ((slot ^ (row & 7)) << 3)] = v;
        }
        __syncthreads();

        #pragma unroll
        for (int ks = 0; ks < 2; ++ks) {
            s16x8 af[4], bf_[4];
            int s = ks * 4 + (lane >> 4);
            #pragma unroll
            for (int i = 0; i < 4; ++i) {
                int ar = wm * 64 + i * 16 + (lane & 15);
                af[i]  = *(const s16x8*)&Als[ar * 64 + ((s ^ (ar & 7)) << 3)];
                int br = wn * 64 + i * 16 + (lane & 15);
                bf_[i] = *(const s16x8*)&Bls[br * 64 + ((s ^ (br & 7)) << 3)];
            }
            #pragma unroll
            for (int i = 0; i < 4; ++i)
                #pragma unroll
                for (int j = 0; j < 4; ++j)
                    acc[i][j] = __builtin_amdgcn_mfma_f32_16x16x32_bf16(
                        af[i], bf_[j], acc[i][j], 0, 0, 0);
        }
        __syncthreads();
    }

    // ---- epilogue: C/D map col=lane&15, row=(lane>>4)*4+r ----
    if constexpr (MODE == 5) {
        // hidden=tanh(x+bo1); raw = hidden . Wo2, reduced in-block
        #pragma unroll
        for (int mi = 0; mi < 4; ++mi) {
            #pragma unroll
            for (int r = 0; r < 4; ++r) {
                float s = 0.f;
                #pragma unroll
                for (int ni = 0; ni < 4; ++ni) {
                    int col = wn * 64 + ni * 16 + (lane & 15);
                    float hv = tanhf(acc[mi][ni][r] + bias[col]);
                    s += hv * Wo2[col];
                }
                #pragma unroll
                for (int o = 1; o <= 8; o <<= 1) s += __shfl_xor(s, o, 64);
                if ((lane & 15) == 0)
                    rawp[wm * 64 + mi * 16 + ((lane >> 4) << 2) + r][wn] = s;
            }
        }
        __syncthreads();
        if (t < 128) {
            int m = m0 + t;
            if (m < MROWS) rawout[m] = rawp[t][0] + rawp[t][1] + bo2[0];
        }
        return;
    }

    #pragma unroll
    for (int mi = 0; mi < 4; ++mi) {
        #pragma unroll
        for (int ni = 0; ni < 4; ++ni) {
            f32x4 v = acc[mi][ni];
            int col   = n0 + wn * 64 + ni * 16 + (lane & 15);
            int rbase = m0 + wm * 64 + mi * 16 + ((lane >> 4) << 2);
            if constexpr (MODE == 2) {
                // transposed store: hT[b][col][n]
                if (rbase < MROWS) {
                    int b0 = rbase / NN, nr = rbase - b0 * NN;
                    if (nr + 3 < NN && rbase + 3 < MROWS) {
                        int len = nlen[b0];
                        s16x4 pk;
                        #pragma unroll
                        for (int r = 0; r < 4; ++r) {
                            float nm = (nr + r < len) ? 1.f : 0.f;
                            pk[r] = f2bf((v[r] + bias[col]) * nm);
                        }
                        *(s16x4*)&Cb[((size_t)(b0 * 512 + col)) * 512 + nr] = pk;
                    } else {
                        #pragma unroll
                        for (int r = 0; r < 4; ++r) {
                            int row = rbase + r;
                            if (row < MROWS) {
                                int b = row / NN, n = row - b * NN;
                                float nm = (n < nlen[b]) ? 1.f : 0.f;
                                Cb[((size_t)(b * 512 + col)) * 512 + n] =
                                    f2bf((v[r] + bias[col]) * nm);
                            }
                        }
                    }
                }
            } else {
                #pragma unroll
                for (int r = 0; r < 4; ++r) {
                    int row = rbase + r;
                    float x = v[r];
                    if constexpr (MODE == 0) {
                        if (row < 400) Cb[(size_t)row * 512 + col] = f2bf(x + bias[col]);
                    } else if constexpr (MODE == 1) {
                        if (row < MROWS) {
                            int b = row / NN, n = row - b * NN;
                            float nm = (n < nlen[b]) ? 1.f : 0.f;
                            float tv = tanhf(x + bias[col]);
                            size_t idx = (size_t)row * 512 + col;
                            Cb[idx] = f2bf(tv);
                            float lm = tv * nm;
                            Cf[idx] = lm;  Cb2[idx] = f2bf(lm);
                        }
                    } else if constexpr (MODE == 3) {
                        if (row < NN)
                            Cb[((size_t)z * NN + row) * 512 + col] = f2bf(x);
                    } else if constexpr (MODE == 4) {
                        if (row < MROWS) {
                            int b = row / NN, n = row - b * NN;
                            float nm = (n < nlen[b]) ? 1.f : 0.f;
                            size_t idx = (size_t)row * 512 + col;
                            float att = nm / (1.f + expf(-(x + bias[col])));
                            float u = bf2f(Ab[idx]);
                            float l = lastf[idx];
                            float o = att * tanhf(u) + (1.f - att) * l;
                            Cf[idx] = o;  Cb[idx] = f2bf(o);
                        }
                    }
                }
            }
        }
    }
}

// W [K][N] fp32 -> WT [N][K] bf16
__global__ __launch_bounds__(256)
void wtrans(const float* __restrict__ W, short* __restrict__ WT, int K, int N)
{
    __shared__ float tile[32][33];
    int n0 = blockIdx.x * 32, k0 = blockIdx.y * 32;
    int tx = threadIdx.x, ty = threadIdx.y;
    for (int i = ty; i < 32; i += 8)
        tile[i][tx] = W[(size_t)(k0 + i) * N + n0 + tx];
    __syncthreads();
    for (int i = ty; i < 32; i += 8)
        WT[(size_t)(n0 + i) * K + k0 + tx] = f2bf(tile[tx][i]);
}

// adjsumI bf16 [16][512][512] = sum_r adj + I, zero-padded (bf16 exact: 0..4)
__global__ __launch_bounds__(256)
void adjsum_conv(const float* __restrict__ adj, short* __restrict__ out)
{
    int i = blockIdx.x * 256 + threadIdx.x;
    int b = i >> 18;
    int rem = i & (512 * 512 - 1);
    int n = rem >> 9, m = rem & 511;
    float v = 0.f;
    if (n < NN && m < NN) {
        const float* base = adj + (((size_t)b * RR) * NN + n) * NN + m;
        v = base[0] + base[(size_t)NN * NN] + base[2 * (size_t)NN * NN];
        if (n == m) v += 1.f;
    }
    out[i] = f2bf(v);
}

// ---------------------------------------------------------------------------
// sim + softmax + n2q + simmax: block = 256 threads, 16 nodes per block.
// grid (32 node-tiles, 16 b). query staged in LDS bf16 (stride 520).
// ---------------------------------------------------------------------------
__global__ __launch_bounds__(256)
void sim_n2q2(const float* __restrict__ last_f, const short* __restrict__ query_b,
              const float* __restrict__ Wa, short* __restrict__ n2q_b,
              float* __restrict__ simmax)
{
    __shared__ short qL[32 * 520];   // rows 0..24 valid
    __shared__ short cfL[16 * 520];
    __shared__ float pL[16 * 32];

    const int t = threadIdx.x;
    const int b = blockIdx.y;
    const int nbase = blockIdx.x * 16;
    const int nl = t >> 4, c = t & 15;
    const int n = nbase + nl;
    const bool valid = (n < NN);
    const int rowg = b * NN + (valid ? n : NN - 1);

    // Phase A: stage query[b] (25x512) into LDS
    for (int i = t; i < 1600; i += 256) {
        int q = i >> 6, dc = i & 63;
        s16x8 v = *(const s16x8*)(query_b + ((size_t)b * QQ + q) * 512 + dc * 8);
        *(s16x8*)&qL[q * 520 + dc * 8] = v;
    }

    // Phase B: coef[nl][d] = wq[d] + last*ws[d] (bf16); apart = sum last*wn_
    float apart = 0.f;
    {
        const float* lr = last_f + (size_t)rowg * 512 + c * 32;
        s16x8 pk[4];
        #pragma unroll
        for (int j = 0; j < 32; ++j) {
            int d = c * 32 + j;
            float lv = lr[j];
            apart += lv * Wa[d];
            pk[j >> 3][j & 7] = f2bf(Wa[512 + d] + lv * Wa[1024 + d]);
        }
        #pragma unroll
        for (int jj = 0; jj < 4; ++jj)
            *(s16x8*)&cfL[nl * 520 + c * 32 + jj * 8] = pk[jj];
        #pragma unroll
        for (int o = 1; o <= 8; o <<= 1) apart += __shfl_xor(apart, o, 64);
    }
    __syncthreads();

    // Phase C: sim for q=c and q=c+16; softmax over q (25 valid)
    float sum1 = 0.f, sum2 = 0.f;
    const bool q2v = (c < 9);   // c+16 < 25
    #pragma unroll 8
    for (int dc = 0; dc < 64; ++dc) {
        s16x8 cf8 = *(const s16x8*)&cfL[nl * 520 + dc * 8];
        s16x8 qa  = *(const s16x8*)&qL[c * 520 + dc * 8];
        s16x8 qb2 = *(const s16x8*)&qL[(c + 16) * 520 + dc * 8];
        #pragma unroll
        for (int e = 0; e < 8; ++e) {
            float cf = bf2f(cf8[e]);
            sum1 += cf * bf2f(qa[e]);
            sum2 += cf * bf2f(qb2[e]);
        }
    }
    float s1 = apart + sum1;
    float s2 = q2v ? (apart + sum2) : -INFINITY;
    float m = fmaxf(s1, s2);
    #pragma unroll
    for (int o = 1; o <= 8; o <<= 1) m = fmaxf(m, __shfl_xor(m, o, 64));
    float e1 = expf(s1 - m);
    float e2 = q2v ? expf(s2 - m) : 0.f;
    float den = e1 + e2;
    #pragma unroll
    for (int o = 1; o <= 8; o <<= 1) den += __shfl_xor(den, o, 64);
    float inv = 1.f / den;
    pL[nl * 32 + c]      = e1 * inv;
    pL[nl * 32 + c + 16] = e2 * inv;
    if (c == 0 && valid) simmax[b * NN + n] = m;
    __syncthreads();

    // Phase D: n2q[nl][d] = sum_q p*query ; d = jj*128 + c*8 + e
    float accv[4][8];
    #pragma unroll
    for (int jj = 0; jj < 4; ++jj)
        #pragma unroll
        for (int e = 0; e < 8; ++e) accv[jj][e] = 0.f;
    for (int q = 0; q < QQ; ++q) {
        float p = pL[nl * 32 + q];
        #pragma unroll
        for (int jj = 0; jj < 4; ++jj) {
            s16x8 q8 = *(const s16x8*)&qL[q * 520 + (jj * 16 + c) * 8];
            #pragma unroll
            for (int e = 0; e < 8; ++e) accv[jj][e] += p * bf2f(q8[e]);
        }
    }
    if (valid) {
        #pragma unroll
        for (int jj = 0; jj < 4; ++jj) {
            s16x8 o8;
            #pragma unroll
            for (int e = 0; e < 8; ++e) o8[e] = f2bf(accv[jj][e]);
            *(s16x8*)(n2q_b + ((size_t)b * NN + n) * 512 + jj * 128 + c * 8) = o8;
        }
    }
}

// b_att softmax over n + q2n; grid (8 d-blocks, 16 b)
__global__ __launch_bounds__(256)
void batt_q2n2(const float* __restrict__ simmax, const short* __restrict__ nc_b,
               short* __restrict__ q2n_b)
{
    __shared__ float pL[NN];
    __shared__ float red[4];
    __shared__ float part[4][64];
    const int b = blockIdx.y, d0 = blockIdx.x * 64;
    const int t = threadIdx.x, wv = t >> 6, lane = t & 63;
    const float* sm = simmax + (size_t)b * NN;

    float m = -INFINITY;
    for (int n = t; n < NN; n += 256) m = fmaxf(m, sm[n]);
    #pragma unroll
    for (int o = 32; o >= 1; o >>= 1) m = fmaxf(m, __shfl_xor(m, o, 64));
    if (lane == 0) red[wv] = m;
    __syncthreads();
    float M4 = fmaxf(fmaxf(red[0], red[1]), fmaxf(red[2], red[3]));
    __syncthreads();

    float den = 0.f;
    for (int n = t; n < NN; n += 256) { float e = expf(sm[n] - M4); pL[n] = e; den += e; }
    #pragma unroll
    for (int o = 32; o >= 1; o >>= 1) den += __shfl_xor(den, o, 64);
    if (lane == 0) red[wv] = den;
    __syncthreads();
    float invD = 1.f / (red[0] + red[1] + red[2] + red[3]);

    int d = d0 + (t & 63);
    int pi = t >> 6;
    float acc = 0.f;
    for (int n = pi * 125; n < pi * 125 + 125; ++n)
        acc += pL[n] * bf2f(nc_b[((size_t)b * NN + n) * 512 + d]);
    part[pi][t & 63] = acc;
    __syncthreads();
    if (t < 64)
        q2n_b[(size_t)b * 512 + d0 + t] =
            f2bf((part[0][t] + part[1][t] + part[2][t] + part[3][t]) * invD);
}

__global__ __launch_bounds__(64)
void out_kernel(const int* __restrict__ mask, const float* __restrict__ raw,
                float* __restrict__ out)
{
    int bc = blockIdx.x;
    int b  = bc / CC;
    int lane = threadIdx.x;
    const int*   mrow = mask + (size_t)bc * NN;
    const float* rrow = raw  + (size_t)b * NN;
    float mx = -INFINITY;
    for (int n = lane; n < NN; n += 64) {
        float v = (float)mrow[n] * rrow[n];
        v = (v == 0.f) ? -INFINITY : v;
        mx = fmaxf(mx, v);
    }
    #pragma unroll
    for (int o = 32; o >= 1; o >>= 1) mx = fmaxf(mx, __shfl_xor(mx, o, 64));
    if (lane == 0) out[bc] = mx;
}

extern "C" void kernel_launch(void* const* d_in, const int* in_sizes, int n_in,
                              void* d_out, int out_size, void* d_ws, size_t ws_size,
                              hipStream_t stream)
{
    const float* nodes_elmo = (const float*)d_in[0];
    const float* query_elmo = (const float*)d_in[1];
    const float* adj        = (const float*)d_in[2];
    const int*   mask       = (const int*)  d_in[3];
    const int*   nlen       = (const int*)  d_in[4];
    const float* Wq  = (const float*)d_in[6];
    const float* bq  = (const float*)d_in[7];
    const float* Wn  = (const float*)d_in[8];
    const float* bn  = (const float*)d_in[9];
    const float* Wh  = (const float*)d_in[10];
    const float* bh  = (const float*)d_in[11];
    const float* Wc  = (const float*)d_in[12];
    const float* bc  = (const float*)d_in[13];
    const float* Wa  = (const float*)d_in[14];
    const float* Wo1 = (const float*)d_in[15];
    const float* bo1 = (const float*)d_in[16];
    const float* Wo2 = (const float*)d_in[17];
    const float* bo2 = (const float*)d_in[18];
    float* out = (float*)d_out;

    char* p = (char*)d_ws;
    auto carveF = [&](size_t n) { float* r = (float*)p; p += n * 4; return r; };
    auto carveS = [&](size_t n) { short* r = (short*)p; p += n * 2; return r; };

    float* last_f0   = carveF((size_t)MROWS * 512);
    float* last_f1   = carveF((size_t)MROWS * 512);
    float* simmax    = carveF(MROWS);
    float* raw       = carveF(MROWS + 64);
    short* nodes_bf  = carveS((size_t)MROWS * EE);      // 24.58M
    short* qelmo_bf  = carveS((size_t)400 * EE);
    short* query_b   = carveS((size_t)400 * 512);
    short* nc_b      = carveS((size_t)MROWS * 512);
    short* last_b0   = carveS((size_t)MROWS * 512);
    short* last_b1   = carveS((size_t)MROWS * 512);
    short* hT_b      = carveS((size_t)BB * 512 * 512);
    short* update_b  = carveS((size_t)MROWS * 512);
    short* n2q_b     = carveS((size_t)MROWS * 512);
    short* adjsum_b  = carveS((size_t)BB * 512 * 512);
    short* q2n_b     = carveS((size_t)BB * 512);
    short* WqT       = carveS((size_t)512 * 3072);
    short* WnT       = carveS((size_t)512 * 3072);
    short* WhT       = carveS((size_t)512 * 512);
    short* WcT       = carveS((size_t)512 * 1024);
    short* Wo1T      = carveS((size_t)128 * 2048);

    dim3 tb(32, 8);

    // input conversions
    cvt_bf16<<<(MROWS * EE) / (256 * 8), 256, 0, stream>>>(nodes_elmo, nodes_bf, MROWS * EE);
    cvt_bf16<<<(400 * EE) / (256 * 8), 256, 0, stream>>>(query_elmo, qelmo_bf, 400 * EE);

    // weight transposes
    wtrans<<<dim3(16, 96), tb, 0, stream>>>(Wq,  WqT,  3072, 512);
    wtrans<<<dim3(16, 96), tb, 0, stream>>>(Wn,  WnT,  3072, 512);
    wtrans<<<dim3(16, 16), tb, 0, stream>>>(Wh,  WhT,  512,  512);
    wtrans<<<dim3(16, 32), tb, 0, stream>>>(Wc,  WcT,  1024, 512);
    wtrans<<<dim3(4,  64), tb, 0, stream>>>(Wo1, Wo1T, 2048, 128);

    adjsum_conv<<<(BB * 512 * 512) / 256, 256, 0, stream>>>(adj, adjsum_b);

    // query = qelmo @ Wq + bq (bf16)
    gemm_mfma<0><<<dim3(4, 4), 256, 0, stream>>>(
        qelmo_bf, nullptr, WqT, bq, nullptr, query_b, nullptr,
        nullptr, nullptr, nullptr, nullptr, nullptr, nullptr, nullptr,
        400, 3072, 512, 399);

    // nc = tanh(nodes@Wn+bn); last0 = nc*nmask
    gemm_mfma<1><<<dim3(4, 63), 256, 0, stream>>>(
        nodes_bf, nullptr, WnT, bn, last_f0, nc_b, last_b0,
        nullptr, nullptr, nullptr, nullptr, nullptr, nullptr, nlen,
        MROWS, 3072, 512, MROWS - 1);

    float* lf_cur = last_f0; float* lf_nxt = last_f1;
    short* lb_cur = last_b0; short* lb_nxt = last_b1;
    for (int hop = 0; hop < HOPS; ++hop) {
        // hT = ((last @ Wh + bh)*nmask)^T per b
        gemm_mfma<2><<<dim3(4, 63), 256, 0, stream>>>(
            lb_cur, nullptr, WhT, bh, nullptr, hT_b, nullptr,
            nullptr, nullptr, nullptr, nullptr, nullptr, nullptr, nlen,
            MROWS, 512, 512, MROWS - 1);

        // update = (adjsum+I) @ h
        gemm_mfma<3><<<dim3(4, 4, 16), 256, 0, stream>>>(
            adjsum_b, nullptr, hT_b, nullptr, nullptr, update_b, nullptr,
            nullptr, nullptr, nullptr, nullptr, nullptr, nullptr, nullptr,
            NN, 512, 512, 511);

        // gate
        gemm_mfma<4><<<dim3(4, 63), 256, 0, stream>>>(
            update_b, lb_cur, WcT, bc, lf_nxt, lb_nxt, nullptr,
            lf_cur, nullptr, nullptr, nullptr, nullptr, nullptr, nlen,
            MROWS, 1024, 512, MROWS - 1);

        float* tf = lf_cur; lf_cur = lf_nxt; lf_nxt = tf;
        short* ts = lb_cur; lb_cur = lb_nxt; lb_nxt = ts;
    }

    sim_n2q2<<<dim3(32, 16), 256, 0, stream>>>(lf_cur, query_b, Wa, n2q_b, simmax);
    batt_q2n2<<<dim3(8, 16), 256, 0, stream>>>(simmax, nc_b, q2n_b);

    // hidden=tanh(g@Wo1+bo1); raw fused
    gemm_mfma<5><<<dim3(1, 63), 256, 0, stream>>>(
        nc_b, nullptr, Wo1T, bo1, nullptr, nullptr, nullptr,
        nullptr, n2q_b, q2n_b, Wo2, bo2, raw, nullptr,
        MROWS, 2048, 128, MROWS - 1);

    out_kernel<<<BB * CC, 64, 0, stream>>>(mask, raw, out);
}

// Round 5
// 727.220 us; speedup vs baseline: 5.1526x; 1.2885x over previous
//
#include <hip/hip_runtime.h>
#include <hip/hip_bf16.h>
#include <math.h>

// Problem constants
#define BB 16
#define NN 500
#define QQ 25
#define CC 80
#define RR 3
#define DD 512
#define EE 3072
#define HOPS 5
#define MROWS (BB*NN)   // 8000

typedef float f32x4  __attribute__((ext_vector_type(4)));
typedef short s16x8  __attribute__((ext_vector_type(8)));
typedef short s16x4  __attribute__((ext_vector_type(4)));

static __device__ __forceinline__ short f2bf(float x) {
    __hip_bfloat16 h = __float2bfloat16(x);
    return __builtin_bit_cast(short, h);
}
static __device__ __forceinline__ float bf2f(short s) {
    __hip_bfloat16 h = __builtin_bit_cast(__hip_bfloat16, s);
    return __bfloat162float(h);
}

// ---------------------------------------------------------------------------
// Pipelined MFMA GEMM. BMx128 tile, BK=64, 256 threads = 4 waves.
//   BM=128: wave=64x64 (MI=4);  BM=64: wave=32x64 (MI=2).
// Ping-pong double-buffered LDS, 1 barrier/iter:
//   iter kt: {issue glob->reg loads for kt+1} {MFMA buf[kt&1]} {reg->LDS
//   buf[(kt+1)&1]} {barrier}.  Peers' reads of buf[(kt+1)&1] finished before
//   the PREVIOUS iteration's barrier, so a single end-of-iter barrier is safe.
// XOR-swizzled LDS (16B chunk ^ row&7) -> conflict-free ds_read_b128.
// MODE 0: query_b = A@W + bias (A fp32, bf16 out)
// MODE 1: nc=tanh(A@W+b) -> nc_b; last = nc*nmask -> last_f (f32) + last_b
// MODE 2: h = (A@W+b)*nmask written TRANSPOSED -> hT[b][d][n] bf16
// MODE 3: update[z] = (adjsum+I)[z] @ hT[z]  -> bf16 row-major (batched z)
// MODE 4: gate: att=sig([u|l]@Wc+b)*nm; out=att*tanh(u)+(1-att)*l (f32+bf16)
// MODE 5: hidden=tanh(g@Wo1+b); raw[m]=hidden·Wo2+bo2 fused (g generated)
// ---------------------------------------------------------------------------
template<int MODE, int KT, int BM>
__global__ __launch_bounds__(256)
void gemm_mfma(const float* __restrict__ Af,
               const short* __restrict__ Ab, const short* __restrict__ Ab2,
               const short* __restrict__ Bt, const float* __restrict__ bias,
               float* __restrict__ Cf, short* __restrict__ Cb,
               short* __restrict__ Cb2, const float* __restrict__ lastf,
               const short* __restrict__ n2qb, const short* __restrict__ q2nb,
               const float* __restrict__ Wo2, const float* __restrict__ bo2,
               float* __restrict__ rawout,
               const int* __restrict__ nlen,
               int mclamp)
{
    constexpr int MI  = BM / 32;     // acc row-fragments per wave
    constexpr int ACH = BM / 32;     // A 16B-chunks per thread
    constexpr int NKT = KT / 64;

    __shared__ short Als[2 * BM * 64];
    __shared__ short Bls[2 * 128 * 64];
    __shared__ float rawp[BM][2];

    const int t    = threadIdx.x;
    const int lane = t & 63;
    const int w    = t >> 6;
    const int wm   = w >> 1;
    const int wn   = w & 1;
    const int n0   = blockIdx.x * 128;
    const int m0   = blockIdx.y * BM;
    const int z    = blockIdx.z;
    const size_t za = (MODE == 3) ? (size_t)z * (512 * 512) : 0;

    // stage coordinates (kt-invariant)
    int arow[ACH], aslot[ACH], arg_[ACH];
    #pragma unroll
    for (int c = 0; c < ACH; ++c) {
        int f = c * 256 + t;
        arow[c] = f >> 3;  aslot[c] = f & 7;
        int rg = m0 + arow[c]; if (rg > mclamp) rg = mclamp;
        arg_[c] = rg;
    }
    int brow[4], bslot[4];
    #pragma unroll
    for (int c = 0; c < 4; ++c) {
        int f = c * 256 + t;
        brow[c] = f >> 3;  bslot[c] = f & 7;
    }

    // prefetch registers
    f32x4 paf[ACH][2];
    s16x8 pa[ACH], pao[ACH], pb[4];

    auto stage_regs = [&](int kt) {
        #pragma unroll
        for (int c = 0; c < ACH; ++c) {
            int k = kt * 64 + aslot[c] * 8;
            if constexpr (MODE <= 1) {
                const float* s = Af + (size_t)arg_[c] * KT + k;
                paf[c][0] = *(const f32x4*)s;
                paf[c][1] = *(const f32x4*)(s + 4);
            } else if constexpr (MODE == 2) {
                pa[c] = *(const s16x8*)(Ab + (size_t)arg_[c] * 512 + k);
            } else if constexpr (MODE == 3) {
                pa[c] = *(const s16x8*)(Ab + za + (size_t)arg_[c] * 512 + k);
            } else if constexpr (MODE == 4) {
                pa[c] = (k < 512)
                    ? *(const s16x8*)(Ab  + (size_t)arg_[c] * 512 + k)
                    : *(const s16x8*)(Ab2 + (size_t)arg_[c] * 512 + (k - 512));
            } else { // MODE 5: g = [nc, n2q, nc*n2q, nc*q2n]
                int seg = k >> 9, off = k & 511;
                const short* p1 = (seg == 1) ? n2qb : Ab;
                pa[c] = *(const s16x8*)(p1 + (size_t)arg_[c] * 512 + off);
                if (seg >= 2) {
                    const short* p2 = (seg == 2)
                        ? n2qb + (size_t)arg_[c] * 512 + off
                        : q2nb + (size_t)(arg_[c] / NN) * 512 + off;
                    pao[c] = *(const s16x8*)p2;
                }
            }
        }
        #pragma unroll
        for (int c = 0; c < 4; ++c) {
            int k = kt * 64 + bslot[c] * 8;
            pb[c] = *(const s16x8*)(Bt + za + (size_t)(n0 + brow[c]) * KT + k);
        }
    };

    auto write_lds = [&](int bsel, int kt) {
        const int offA = bsel * BM * 64, offB = bsel * 128 * 64;
        #pragma unroll
        for (int c = 0; c < ACH; ++c) {
            s16x8 v;
            if constexpr (MODE <= 1) {
                #pragma unroll
                for (int j = 0; j < 4; ++j) {
                    v[j]     = f2bf(paf[c][0][j]);
                    v[4 + j] = f2bf(paf[c][1][j]);
                }
            } else if constexpr (MODE == 5) {
                int k = kt * 64 + aslot[c] * 8;
                int seg = k >> 9;
                v = pa[c];
                if (seg >= 2) {
                    #pragma unroll
                    for (int j = 0; j < 8; ++j)
                        v[j] = f2bf(bf2f(pa[c][j]) * bf2f(pao[c][j]));
                }
            } else {
                v = pa[c];
            }
            *(s16x8*)&Als[offA + arow[c] * 64 + ((aslot[c] ^ (arow[c] & 7)) << 3)] = v;
        }
        #pragma unroll
        for (int c = 0; c < 4; ++c)
            *(s16x8*)&Bls[offB + brow[c] * 64 + ((bslot[c] ^ (brow[c] & 7)) << 3)] = pb[c];
    };

    f32x4 acc[MI][4];
    #pragma unroll
    for (int i = 0; i < MI; ++i)
        #pragma unroll
        for (int j = 0; j < 4; ++j)
            acc[i][j] = (f32x4){0.f, 0.f, 0.f, 0.f};

    auto mfma_step = [&](int bsel) {
        const int offA = bsel * BM * 64, offB = bsel * 128 * 64;
        #pragma unroll
        for (int ks = 0; ks < 2; ++ks) {
            s16x8 af[MI], bfr[4];
            int s = ks * 4 + (lane >> 4);
            #pragma unroll
            for (int i = 0; i < MI; ++i) {
                int ar = wm * (MI * 16) + i * 16 + (lane & 15);
                af[i] = *(const s16x8*)&Als[offA + ar * 64 + ((s ^ (ar & 7)) << 3)];
            }
            #pragma unroll
            for (int j = 0; j < 4; ++j) {
                int br = wn * 64 + j * 16 + (lane & 15);
                bfr[j] = *(const s16x8*)&Bls[offB + br * 64 + ((s ^ (br & 7)) << 3)];
            }
            #pragma unroll
            for (int i = 0; i < MI; ++i)
                #pragma unroll
                for (int j = 0; j < 4; ++j)
                    acc[i][j] = __builtin_amdgcn_mfma_f32_16x16x32_bf16(
                        af[i], bfr[j], acc[i][j], 0, 0, 0);
        }
    };

    // ---- pipelined main loop ----
    stage_regs(0);
    write_lds(0, 0);
    __syncthreads();
    for (int kt = 0; kt < NKT - 1; ++kt) {
        stage_regs(kt + 1);          // issue loads (hidden under MFMA)
        mfma_step(kt & 1);
        write_lds((kt + 1) & 1, kt + 1);
        __syncthreads();
    }
    mfma_step((NKT - 1) & 1);

    // ---- epilogue: C/D map col=lane&15, row=(lane>>4)*4+r ----
    if constexpr (MODE == 5) {
        #pragma unroll
        for (int mi = 0; mi < MI; ++mi) {
            #pragma unroll
            for (int r = 0; r < 4; ++r) {
                float s = 0.f;
                #pragma unroll
                for (int ni = 0; ni < 4; ++ni) {
                    int col = wn * 64 + ni * 16 + (lane & 15);
                    float hv = tanhf(acc[mi][ni][r] + bias[col]);
                    s += hv * Wo2[col];
                }
                #pragma unroll
                for (int o = 1; o <= 8; o <<= 1) s += __shfl_xor(s, o, 64);
                if ((lane & 15) == 0)
                    rawp[wm * (MI * 16) + mi * 16 + ((lane >> 4) << 2) + r][wn] = s;
            }
        }
        __syncthreads();
        if (t < BM) {
            int m = m0 + t;
            if (m < MROWS) rawout[m] = rawp[t][0] + rawp[t][1] + bo2[0];
        }
        return;
    }

    #pragma unroll
    for (int mi = 0; mi < MI; ++mi) {
        #pragma unroll
        for (int ni = 0; ni < 4; ++ni) {
            f32x4 v = acc[mi][ni];
            int col   = n0 + wn * 64 + ni * 16 + (lane & 15);
            int rbase = m0 + wm * (MI * 16) + mi * 16 + ((lane >> 4) << 2);
            if constexpr (MODE == 2) {
                // transposed store: hT[b][col][n]
                if (rbase < MROWS) {
                    int b0 = rbase / NN, nr = rbase - b0 * NN;
                    if (nr + 3 < NN && rbase + 3 < MROWS) {
                        int len = nlen[b0];
                        s16x4 pk;
                        #pragma unroll
                        for (int r = 0; r < 4; ++r) {
                            float nm = (nr + r < len) ? 1.f : 0.f;
                            pk[r] = f2bf((v[r] + bias[col]) * nm);
                        }
                        *(s16x4*)&Cb[((size_t)(b0 * 512 + col)) * 512 + nr] = pk;
                    } else {
                        #pragma unroll
                        for (int r = 0; r < 4; ++r) {
                            int row = rbase + r;
                            if (row < MROWS) {
                                int b = row / NN, n = row - b * NN;
                                float nm = (n < nlen[b]) ? 1.f : 0.f;
                                Cb[((size_t)(b * 512 + col)) * 512 + n] =
                                    f2bf((v[r] + bias[col]) * nm);
                            }
                        }
                    }
                }
            } else {
                #pragma unroll
                for (int r = 0; r < 4; ++r) {
                    int row = rbase + r;
                    float x = v[r];
                    if constexpr (MODE == 0) {
                        if (row < 400) Cb[(size_t)row * 512 + col] = f2bf(x + bias[col]);
                    } else if constexpr (MODE == 1) {
                        if (row < MROWS) {
                            int b = row / NN, n = row - b * NN;
                            float nm = (n < nlen[b]) ? 1.f : 0.f;
                            float tv = tanhf(x + bias[col]);
                            size_t idx = (size_t)row * 512 + col;
                            Cb[idx] = f2bf(tv);
                            float lm = tv * nm;
                            Cf[idx] = lm;  Cb2[idx] = f2bf(lm);
                        }
                    } else if constexpr (MODE == 3) {
                        if (row < NN)
                            Cb[((size_t)z * NN + row) * 512 + col] = f2bf(x);
                    } else if constexpr (MODE == 4) {
                        if (row < MROWS) {
                            int b = row / NN, n = row - b * NN;
                            float nm = (n < nlen[b]) ? 1.f : 0.f;
                            size_t idx = (size_t)row * 512 + col;
                            float att = nm / (1.f + expf(-(x + bias[col])));
                            float u = bf2f(Ab[idx]);
                            float l = lastf[idx];
                            float o = att * tanhf(u) + (1.f - att) * l;
                            Cf[idx] = o;  Cb[idx] = f2bf(o);
                        }
                    }
                }
            }
        }
    }
}

// All 5 weight transposes in ONE dispatch (z selects weight). fp32 [K][N]
// -> bf16 [N][K].
__global__ __launch_bounds__(256)
void wtrans_all(const float* __restrict__ W0, const float* __restrict__ W1,
                const float* __restrict__ W2, const float* __restrict__ W3,
                const float* __restrict__ W4,
                short* __restrict__ O0, short* __restrict__ O1,
                short* __restrict__ O2, short* __restrict__ O3,
                short* __restrict__ O4)
{
    const int z = blockIdx.z;
    int K, N; const float* W; short* O;
    if      (z == 0) { K = 3072; N = 512; W = W0; O = O0; }
    else if (z == 1) { K = 3072; N = 512; W = W1; O = O1; }
    else if (z == 2) { K = 512;  N = 512; W = W2; O = O2; }
    else if (z == 3) { K = 1024; N = 512; W = W3; O = O3; }
    else             { K = 2048; N = 128; W = W4; O = O4; }
    int n0 = blockIdx.x * 32, k0 = blockIdx.y * 32;
    if (n0 >= N || k0 >= K) return;
    __shared__ float tile[32][33];
    int tx = threadIdx.x, ty = threadIdx.y;
    for (int i = ty; i < 32; i += 8)
        tile[i][tx] = W[(size_t)(k0 + i) * N + n0 + tx];
    __syncthreads();
    for (int i = ty; i < 32; i += 8)
        O[(size_t)(n0 + i) * K + k0 + tx] = f2bf(tile[tx][i]);
}

// adjsumI bf16 [16][512][512] = sum_r adj + I, zero-padded (bf16 exact: 0..4)
__global__ __launch_bounds__(256)
void adjsum_conv(const float* __restrict__ adj, short* __restrict__ out)
{
    int i = blockIdx.x * 256 + threadIdx.x;
    int b = i >> 18;
    int rem = i & (512 * 512 - 1);
    int n = rem >> 9, m = rem & 511;
    float v = 0.f;
    if (n < NN && m < NN) {
        const float* base = adj + (((size_t)b * RR) * NN + n) * NN + m;
        v = base[0] + base[(size_t)NN * NN] + base[2 * (size_t)NN * NN];
        if (n == m) v += 1.f;
    }
    out[i] = f2bf(v);
}

// ---------------------------------------------------------------------------
// sim + softmax + n2q + simmax: block = 256 threads, 16 nodes per block.
// ---------------------------------------------------------------------------
__global__ __launch_bounds__(256)
void sim_n2q2(const float* __restrict__ last_f, const short* __restrict__ query_b,
              const float* __restrict__ Wa, short* __restrict__ n2q_b,
              float* __restrict__ simmax)
{
    __shared__ short qL[32 * 520];   // rows 0..24 valid
    __shared__ short cfL[16 * 520];
    __shared__ float pL[16 * 32];

    const int t = threadIdx.x;
    const int b = blockIdx.y;
    const int nbase = blockIdx.x * 16;
    const int nl = t >> 4, c = t & 15;
    const int n = nbase + nl;
    const bool valid = (n < NN);
    const int rowg = b * NN + (valid ? n : NN - 1);

    for (int i = t; i < 1600; i += 256) {
        int q = i >> 6, dc = i & 63;
        s16x8 v = *(const s16x8*)(query_b + ((size_t)b * QQ + q) * 512 + dc * 8);
        *(s16x8*)&qL[q * 520 + dc * 8] = v;
    }

    float apart = 0.f;
    {
        const float* lr = last_f + (size_t)rowg * 512 + c * 32;
        s16x8 pk[4];
        #pragma unroll
        for (int j = 0; j < 32; ++j) {
            int d = c * 32 + j;
            float lv = lr[j];
            apart += lv * Wa[d];
            pk[j >> 3][j & 7] = f2bf(Wa[512 + d] + lv * Wa[1024 + d]);
        }
        #pragma unroll
        for (int jj = 0; jj < 4; ++jj)
            *(s16x8*)&cfL[nl * 520 + c * 32 + jj * 8] = pk[jj];
        #pragma unroll
        for (int o = 1; o <= 8; o <<= 1) apart += __shfl_xor(apart, o, 64);
    }
    __syncthreads();

    float sum1 = 0.f, sum2 = 0.f;
    const bool q2v = (c < 9);
    #pragma unroll 8
    for (int dc = 0; dc < 64; ++dc) {
        s16x8 cf8 = *(const s16x8*)&cfL[nl * 520 + dc * 8];
        s16x8 qa  = *(const s16x8*)&qL[c * 520 + dc * 8];
        s16x8 qb2 = *(const s16x8*)&qL[(c + 16) * 520 + dc * 8];
        #pragma unroll
        for (int e = 0; e < 8; ++e) {
            float cf = bf2f(cf8[e]);
            sum1 += cf * bf2f(qa[e]);
            sum2 += cf * bf2f(qb2[e]);
        }
    }
    float s1 = apart + sum1;
    float s2 = q2v ? (apart + sum2) : -INFINITY;
    float m = fmaxf(s1, s2);
    #pragma unroll
    for (int o = 1; o <= 8; o <<= 1) m = fmaxf(m, __shfl_xor(m, o, 64));
    float e1 = expf(s1 - m);
    float e2 = q2v ? expf(s2 - m) : 0.f;
    float den = e1 + e2;
    #pragma unroll
    for (int o = 1; o <= 8; o <<= 1) den += __shfl_xor(den, o, 64);
    float inv = 1.f / den;
    pL[nl * 32 + c]      = e1 * inv;
    pL[nl * 32 + c + 16] = e2 * inv;
    if (c == 0 && valid) simmax[b * NN + n] = m;
    __syncthreads();

    float accv[4][8];
    #pragma unroll
    for (int jj = 0; jj < 4; ++jj)
        #pragma unroll
        for (int e = 0; e < 8; ++e) accv[jj][e] = 0.f;
    for (int q = 0; q < QQ; ++q) {
        float p = pL[nl * 32 + q];
        #pragma unroll
        for (int jj = 0; jj < 4; ++jj) {
            s16x8 q8 = *(const s16x8*)&qL[q * 520 + (jj * 16 + c) * 8];
            #pragma unroll
            for (int e = 0; e < 8; ++e) accv[jj][e] += p * bf2f(q8[e]);
        }
    }
    if (valid) {
        #pragma unroll
        for (int jj = 0; jj < 4; ++jj) {
            s16x8 o8;
            #pragma unroll
            for (int e = 0; e < 8; ++e) o8[e] = f2bf(accv[jj][e]);
            *(s16x8*)(n2q_b + ((size_t)b * NN + n) * 512 + jj * 128 + c * 8) = o8;
        }
    }
}

// b_att softmax over n + q2n; grid (8 d-blocks, 16 b)
__global__ __launch_bounds__(256)
void batt_q2n2(const float* __restrict__ simmax, const short* __restrict__ nc_b,
               short* __restrict__ q2n_b)
{
    __shared__ float pL[NN];
    __shared__ float red[4];
    __shared__ float part[4][64];
    const int b = blockIdx.y, d0 = blockIdx.x * 64;
    const int t = threadIdx.x, wv = t >> 6, lane = t & 63;
    const float* sm = simmax + (size_t)b * NN;

    float m = -INFINITY;
    for (int n = t; n < NN; n += 256) m = fmaxf(m, sm[n]);
    #pragma unroll
    for (int o = 32; o >= 1; o >>= 1) m = fmaxf(m, __shfl_xor(m, o, 64));
    if (lane == 0) red[wv] = m;
    __syncthreads();
    float M4 = fmaxf(fmaxf(red[0], red[1]), fmaxf(red[2], red[3]));
    __syncthreads();

    float den = 0.f;
    for (int n = t; n < NN; n += 256) { float e = expf(sm[n] - M4); pL[n] = e; den += e; }
    #pragma unroll
    for (int o = 32; o >= 1; o >>= 1) den += __shfl_xor(den, o, 64);
    if (lane == 0) red[wv] = den;
    __syncthreads();
    float invD = 1.f / (red[0] + red[1] + red[2] + red[3]);

    int d = d0 + (t & 63);
    int pi = t >> 6;
    float acc = 0.f;
    for (int n = pi * 125; n < pi * 125 + 125; ++n)
        acc += pL[n] * bf2f(nc_b[((size_t)b * NN + n) * 512 + d]);
    part[pi][t & 63] = acc;
    __syncthreads();
    if (t < 64)
        q2n_b[(size_t)b * 512 + d0 + t] =
            f2bf((part[0][t] + part[1][t] + part[2][t] + part[3][t]) * invD);
}

__global__ __launch_bounds__(64)
void out_kernel(const int* __restrict__ mask, const float* __restrict__ raw,
                float* __restrict__ out)
{
    int bc = blockIdx.x;
    int b  = bc / CC;
    int lane = threadIdx.x;
    const int*   mrow = mask + (size_t)bc * NN;
    const float* rrow = raw  + (size_t)b * NN;
    float mx = -INFINITY;
    for (int n = lane; n < NN; n += 64) {
        float v = (float)mrow[n] * rrow[n];
        v = (v == 0.f) ? -INFINITY : v;
        mx = fmaxf(mx, v);
    }
    #pragma unroll
    for (int o = 32; o >= 1; o >>= 1) mx = fmaxf(mx, __shfl_xor(mx, o, 64));
    if (lane == 0) out[bc] = mx;
}

extern "C" void kernel_launch(void* const* d_in, const int* in_sizes, int n_in,
                              void* d_out, int out_size, void* d_ws, size_t ws_size,
                              hipStream_t stream)
{
    const float* nodes_elmo = (const float*)d_in[0];
    const float* query_elmo = (const float*)d_in[1];
    const float* adj        = (const float*)d_in[2];
    const int*   mask       = (const int*)  d_in[3];
    const int*   nlen       = (const int*)  d_in[4];
    const float* Wq  = (const float*)d_in[6];
    const float* bq  = (const float*)d_in[7];
    const float* Wn  = (const float*)d_in[8];
    const float* bn  = (const float*)d_in[9];
    const float* Wh  = (const float*)d_in[10];
    const float* bh  = (const float*)d_in[11];
    const float* Wc  = (const float*)d_in[12];
    const float* bc  = (const float*)d_in[13];
    const float* Wa  = (const float*)d_in[14];
    const float* Wo1 = (const float*)d_in[15];
    const float* bo1 = (const float*)d_in[16];
    const float* Wo2 = (const float*)d_in[17];
    const float* bo2 = (const float*)d_in[18];
    float* out = (float*)d_out;

    char* p = (char*)d_ws;
    auto carveF = [&](size_t n) { float* r = (float*)p; p += n * 4; return r; };
    auto carveS = [&](size_t n) { short* r = (short*)p; p += n * 2; return r; };

    float* last_f0   = carveF((size_t)MROWS * 512);
    float* last_f1   = carveF((size_t)MROWS * 512);
    float* simmax    = carveF(MROWS);
    float* raw       = carveF(MROWS + 64);
    short* query_b   = carveS((size_t)400 * 512);
    short* nc_b      = carveS((size_t)MROWS * 512);
    short* last_b0   = carveS((size_t)MROWS * 512);
    short* last_b1   = carveS((size_t)MROWS * 512);
    short* hT_b      = carveS((size_t)BB * 512 * 512);
    short* update_b  = carveS((size_t)MROWS * 512);
    short* n2q_b     = carveS((size_t)MROWS * 512);
    short* adjsum_b  = carveS((size_t)BB * 512 * 512);
    short* q2n_b     = carveS((size_t)BB * 512);
    short* WqT       = carveS((size_t)512 * 3072);
    short* WnT       = carveS((size_t)512 * 3072);
    short* WhT       = carveS((size_t)512 * 512);
    short* WcT       = carveS((size_t)512 * 1024);
    short* Wo1T      = carveS((size_t)128 * 2048);

    // all weight transposes in one dispatch
    wtrans_all<<<dim3(16, 96, 5), dim3(32, 8), 0, stream>>>(
        Wq, Wn, Wh, Wc, Wo1, WqT, WnT, WhT, WcT, Wo1T);

    adjsum_conv<<<(BB * 512 * 512) / 256, 256, 0, stream>>>(adj, adjsum_b);

    // query = qelmo @ Wq + bq (fp32 in, bf16 out)
    gemm_mfma<0, 3072, 64><<<dim3(4, 7), 256, 0, stream>>>(
        query_elmo, nullptr, nullptr, WqT, bq, nullptr, query_b, nullptr,
        nullptr, nullptr, nullptr, nullptr, nullptr, nullptr, nullptr, 399);

    // nc = tanh(nodes@Wn+bn); last0 = nc*nmask
    gemm_mfma<1, 3072, 128><<<dim3(4, 63), 256, 0, stream>>>(
        nodes_elmo, nullptr, nullptr, WnT, bn, last_f0, nc_b, last_b0,
        nullptr, nullptr, nullptr, nullptr, nullptr, nullptr, nlen, MROWS - 1);

    float* lf_cur = last_f0; float* lf_nxt = last_f1;
    short* lb_cur = last_b0; short* lb_nxt = last_b1;
    for (int hop = 0; hop < HOPS; ++hop) {
        // hT = ((last @ Wh + bh)*nmask)^T per b
        gemm_mfma<2, 512, 64><<<dim3(4, 125), 256, 0, stream>>>(
            nullptr, lb_cur, nullptr, WhT, bh, nullptr, hT_b, nullptr,
            nullptr, nullptr, nullptr, nullptr, nullptr, nullptr, nlen, MROWS - 1);

        // update = (adjsum+I) @ h
        gemm_mfma<3, 512, 64><<<dim3(4, 8, 16), 256, 0, stream>>>(
            nullptr, adjsum_b, nullptr, hT_b, nullptr, nullptr, update_b,
            nullptr, nullptr, nullptr, nullptr, nullptr, nullptr, nullptr,
            nullptr, 511);

        // gate
        gemm_mfma<4, 1024, 64><<<dim3(4, 125), 256, 0, stream>>>(
            nullptr, update_b, lb_cur, WcT, bc, lf_nxt, lb_nxt, nullptr,
            lf_cur, nullptr, nullptr, nullptr, nullptr, nullptr, nlen, MROWS - 1);

        float* tf = lf_cur; lf_cur = lf_nxt; lf_nxt = tf;
        short* ts = lb_cur; lb_cur = lb_nxt; lb_nxt = ts;
    }

    sim_n2q2<<<dim3(32, 16), 256, 0, stream>>>(lf_cur, query_b, Wa, n2q_b, simmax);
    batt_q2n2<<<dim3(8, 16), 256, 0, stream>>>(simmax, nc_b, q2n_b);

    // hidden=tanh(g@Wo1+bo1); raw fused
    gemm_mfma<5, 2048, 64><<<dim3(1, 125), 256, 0, stream>>>(
        nullptr, nc_b, nullptr, Wo1T, bo1, nullptr, nullptr, nullptr,
        nullptr, n2q_b, q2n_b, Wo2, bo2, raw, nullptr, MROWS - 1);

    out_kernel<<<BB * CC, 64, 0, stream>>>(mask, raw, out);
}

// Round 6
// 702.320 us; speedup vs baseline: 5.3352x; 1.0355x over previous
//
#include <hip/hip_runtime.h>
#include <hip/hip_bf16.h>
#include <math.h>

// Problem constants
#define BB 16
#define NN 500
#define QQ 25
#define CC 80
#define RR 3
#define DD 512
#define EE 3072
#define HOPS 5
#define MROWS (BB*NN)   // 8000

typedef float f32x4  __attribute__((ext_vector_type(4)));
typedef short s16x8  __attribute__((ext_vector_type(8)));
typedef short s16x4  __attribute__((ext_vector_type(4)));

static __device__ __forceinline__ short f2bf(float x) {
    __hip_bfloat16 h = __float2bfloat16(x);
    return __builtin_bit_cast(short, h);
}
static __device__ __forceinline__ float bf2f(short s) {
    __hip_bfloat16 h = __builtin_bit_cast(__hip_bfloat16, s);
    return __bfloat162float(h);
}

// ---------------------------------------------------------------------------
// Pipelined MFMA GEMM. BMx128 tile, BK=64, 256 threads = 4 waves (2x2).
//   BM=128: MI=4; BM=64: MI=2; BM=32: MI=1.
// Ping-pong double-buffered LDS, 1 barrier/iter. XOR-swizzled LDS.
// SWZ=0: plain 2D/3D grid.
// SWZ=1: 1D grid; the NB=4 n-blocks of each m-panel get IDs congruent mod 8
//        -> same XCD -> A-panel fetched once into that XCD's L2 (T1).
// SWZ=2: MODE3 batched; all 16 blocks of batch z -> XCD z%8 (A[z]+B[z]=1MB
//        fits L2).
// MODE 0: query_b = A@W + bias (A fp32, bf16 out)
// MODE 1: nc=tanh(A@W+b) -> nc_b; last = nc*nmask -> last_f (f32) + last_b
// MODE 2: h = (A@W+b)*nmask written TRANSPOSED -> hT[b][d][n] bf16
// MODE 3: update[z] = (adjsum+I)[z] @ hT[z]  -> bf16 row-major (batched z)
// MODE 4: gate: att=sig([u|l]@Wc+b)*nm; out=att*tanh(u)+(1-att)*l (f32+bf16)
// MODE 5: hidden=tanh(g@Wo1+b); raw[m]=hidden·Wo2+bo2 fused (g generated)
// ---------------------------------------------------------------------------
template<int MODE, int KT, int BM, int SWZ>
__global__ __launch_bounds__(256)
void gemm_mfma(const float* __restrict__ Af,
               const short* __restrict__ Ab, const short* __restrict__ Ab2,
               const short* __restrict__ Bt, const float* __restrict__ bias,
               float* __restrict__ Cf, short* __restrict__ Cb,
               short* __restrict__ Cb2, const float* __restrict__ lastf,
               const short* __restrict__ n2qb, const short* __restrict__ q2nb,
               const float* __restrict__ Wo2, const float* __restrict__ bo2,
               float* __restrict__ rawout,
               const int* __restrict__ nlen,
               int mclamp)
{
    constexpr int MI  = BM / 32;     // acc row-fragments per wave
    constexpr int ACH = BM / 32;     // A 16B-chunks per thread
    constexpr int NKT = KT / 64;

    __shared__ short Als[2 * BM * 64];
    __shared__ short Bls[2 * 128 * 64];
    __shared__ float rawp[BM][2];

    const int t    = threadIdx.x;
    const int lane = t & 63;
    const int w    = t >> 6;
    const int wm   = w >> 1;
    const int wn   = w & 1;

    int m0, n0, z = 0;
    if constexpr (SWZ == 1) {
        int id = blockIdx.x, r = id & 7, q = id >> 3;
        int pan = r + 8 * (q >> 2);          // panel index, same-XCD groups of 4
        n0 = (q & 3) * 128;  m0 = pan * BM;
        if (m0 > mclamp) return;             // padded panels
    } else if constexpr (SWZ == 2) {
        int id = blockIdx.x, r = id & 7, k = id >> 3;
        z = r + 8 * (k >> 4);                // batch z -> XCD z%8
        int inner = k & 15;
        m0 = (inner >> 2) * BM;  n0 = (inner & 3) * 128;
    } else {
        n0 = blockIdx.x * 128;  m0 = blockIdx.y * BM;  z = blockIdx.z;
    }
    const size_t za = (MODE == 3) ? (size_t)z * (512 * 512) : 0;

    // stage coordinates (kt-invariant)
    int arow[ACH], aslot[ACH], arg_[ACH];
    #pragma unroll
    for (int c = 0; c < ACH; ++c) {
        int f = c * 256 + t;
        arow[c] = f >> 3;  aslot[c] = f & 7;
        int rg = m0 + arow[c]; if (rg > mclamp) rg = mclamp;
        arg_[c] = rg;
    }
    int brow[4], bslot[4];
    #pragma unroll
    for (int c = 0; c < 4; ++c) {
        int f = c * 256 + t;
        brow[c] = f >> 3;  bslot[c] = f & 7;
    }

    // prefetch registers
    f32x4 paf[ACH][2];
    s16x8 pa[ACH], pao[ACH], pb[4];

    auto stage_regs = [&](int kt) {
        #pragma unroll
        for (int c = 0; c < ACH; ++c) {
            int k = kt * 64 + aslot[c] * 8;
            if constexpr (MODE <= 1) {
                const float* s = Af + (size_t)arg_[c] * KT + k;
                paf[c][0] = *(const f32x4*)s;
                paf[c][1] = *(const f32x4*)(s + 4);
            } else if constexpr (MODE == 2) {
                pa[c] = *(const s16x8*)(Ab + (size_t)arg_[c] * 512 + k);
            } else if constexpr (MODE == 3) {
                pa[c] = *(const s16x8*)(Ab + za + (size_t)arg_[c] * 512 + k);
            } else if constexpr (MODE == 4) {
                pa[c] = (k < 512)
                    ? *(const s16x8*)(Ab  + (size_t)arg_[c] * 512 + k)
                    : *(const s16x8*)(Ab2 + (size_t)arg_[c] * 512 + (k - 512));
            } else { // MODE 5: g = [nc, n2q, nc*n2q, nc*q2n]
                int seg = k >> 9, off = k & 511;
                const short* p1 = (seg == 1) ? n2qb : Ab;
                pa[c] = *(const s16x8*)(p1 + (size_t)arg_[c] * 512 + off);
                if (seg >= 2) {
                    const short* p2 = (seg == 2)
                        ? n2qb + (size_t)arg_[c] * 512 + off
                        : q2nb + (size_t)(arg_[c] / NN) * 512 + off;
                    pao[c] = *(const s16x8*)p2;
                }
            }
        }
        #pragma unroll
        for (int c = 0; c < 4; ++c) {
            int k = kt * 64 + bslot[c] * 8;
            pb[c] = *(const s16x8*)(Bt + za + (size_t)(n0 + brow[c]) * KT + k);
        }
    };

    auto write_lds = [&](int bsel, int kt) {
        const int offA = bsel * BM * 64, offB = bsel * 128 * 64;
        #pragma unroll
        for (int c = 0; c < ACH; ++c) {
            s16x8 v;
            if constexpr (MODE <= 1) {
                #pragma unroll
                for (int j = 0; j < 4; ++j) {
                    v[j]     = f2bf(paf[c][0][j]);
                    v[4 + j] = f2bf(paf[c][1][j]);
                }
            } else if constexpr (MODE == 5) {
                int k = kt * 64 + aslot[c] * 8;
                int seg = k >> 9;
                v = pa[c];
                if (seg >= 2) {
                    #pragma unroll
                    for (int j = 0; j < 8; ++j)
                        v[j] = f2bf(bf2f(pa[c][j]) * bf2f(pao[c][j]));
                }
            } else {
                v = pa[c];
            }
            *(s16x8*)&Als[offA + arow[c] * 64 + ((aslot[c] ^ (arow[c] & 7)) << 3)] = v;
        }
        #pragma unroll
        for (int c = 0; c < 4; ++c)
            *(s16x8*)&Bls[offB + brow[c] * 64 + ((bslot[c] ^ (brow[c] & 7)) << 3)] = pb[c];
    };

    f32x4 acc[MI][4];
    #pragma unroll
    for (int i = 0; i < MI; ++i)
        #pragma unroll
        for (int j = 0; j < 4; ++j)
            acc[i][j] = (f32x4){0.f, 0.f, 0.f, 0.f};

    auto mfma_step = [&](int bsel) {
        const int offA = bsel * BM * 64, offB = bsel * 128 * 64;
        #pragma unroll
        for (int ks = 0; ks < 2; ++ks) {
            s16x8 af[MI], bfr[4];
            int s = ks * 4 + (lane >> 4);
            #pragma unroll
            for (int i = 0; i < MI; ++i) {
                int ar = wm * (MI * 16) + i * 16 + (lane & 15);
                af[i] = *(const s16x8*)&Als[offA + ar * 64 + ((s ^ (ar & 7)) << 3)];
            }
            #pragma unroll
            for (int j = 0; j < 4; ++j) {
                int br = wn * 64 + j * 16 + (lane & 15);
                bfr[j] = *(const s16x8*)&Bls[offB + br * 64 + ((s ^ (br & 7)) << 3)];
            }
            #pragma unroll
            for (int i = 0; i < MI; ++i)
                #pragma unroll
                for (int j = 0; j < 4; ++j)
                    acc[i][j] = __builtin_amdgcn_mfma_f32_16x16x32_bf16(
                        af[i], bfr[j], acc[i][j], 0, 0, 0);
        }
    };

    // ---- pipelined main loop ----
    stage_regs(0);
    write_lds(0, 0);
    __syncthreads();
    for (int kt = 0; kt < NKT - 1; ++kt) {
        stage_regs(kt + 1);          // issue loads (hidden under MFMA)
        mfma_step(kt & 1);
        write_lds((kt + 1) & 1, kt + 1);
        __syncthreads();
    }
    mfma_step((NKT - 1) & 1);

    // ---- epilogue: C/D map col=lane&15, row=(lane>>4)*4+r ----
    if constexpr (MODE == 5) {
        #pragma unroll
        for (int mi = 0; mi < MI; ++mi) {
            #pragma unroll
            for (int r = 0; r < 4; ++r) {
                float s = 0.f;
                #pragma unroll
                for (int ni = 0; ni < 4; ++ni) {
                    int col = wn * 64 + ni * 16 + (lane & 15);
                    float hv = tanhf(acc[mi][ni][r] + bias[col]);
                    s += hv * Wo2[col];
                }
                #pragma unroll
                for (int o = 1; o <= 8; o <<= 1) s += __shfl_xor(s, o, 64);
                if ((lane & 15) == 0)
                    rawp[wm * (MI * 16) + mi * 16 + ((lane >> 4) << 2) + r][wn] = s;
            }
        }
        __syncthreads();
        if (t < BM) {
            int m = m0 + t;
            if (m < MROWS) rawout[m] = rawp[t][0] + rawp[t][1] + bo2[0];
        }
        return;
    }

    #pragma unroll
    for (int mi = 0; mi < MI; ++mi) {
        #pragma unroll
        for (int ni = 0; ni < 4; ++ni) {
            f32x4 v = acc[mi][ni];
            int col   = n0 + wn * 64 + ni * 16 + (lane & 15);
            int rbase = m0 + wm * (MI * 16) + mi * 16 + ((lane >> 4) << 2);
            if constexpr (MODE == 2) {
                // transposed store: hT[b][col][n]
                if (rbase < MROWS) {
                    int b0 = rbase / NN, nr = rbase - b0 * NN;
                    if (nr + 3 < NN && rbase + 3 < MROWS) {
                        int len = nlen[b0];
                        s16x4 pk;
                        #pragma unroll
                        for (int r = 0; r < 4; ++r) {
                            float nm = (nr + r < len) ? 1.f : 0.f;
                            pk[r] = f2bf((v[r] + bias[col]) * nm);
                        }
                        *(s16x4*)&Cb[((size_t)(b0 * 512 + col)) * 512 + nr] = pk;
                    } else {
                        #pragma unroll
                        for (int r = 0; r < 4; ++r) {
                            int row = rbase + r;
                            if (row < MROWS) {
                                int b = row / NN, n = row - b * NN;
                                float nm = (n < nlen[b]) ? 1.f : 0.f;
                                Cb[((size_t)(b * 512 + col)) * 512 + n] =
                                    f2bf((v[r] + bias[col]) * nm);
                            }
                        }
                    }
                }
            } else {
                #pragma unroll
                for (int r = 0; r < 4; ++r) {
                    int row = rbase + r;
                    float x = v[r];
                    if constexpr (MODE == 0) {
                        if (row < 400) Cb[(size_t)row * 512 + col] = f2bf(x + bias[col]);
                    } else if constexpr (MODE == 1) {
                        if (row < MROWS) {
                            int b = row / NN, n = row - b * NN;
                            float nm = (n < nlen[b]) ? 1.f : 0.f;
                            float tv = tanhf(x + bias[col]);
                            size_t idx = (size_t)row * 512 + col;
                            Cb[idx] = f2bf(tv);
                            float lm = tv * nm;
                            Cf[idx] = lm;  Cb2[idx] = f2bf(lm);
                        }
                    } else if constexpr (MODE == 3) {
                        if (row < NN)
                            Cb[((size_t)z * NN + row) * 512 + col] = f2bf(x);
                    } else if constexpr (MODE == 4) {
                        if (row < MROWS) {
                            int b = row / NN, n = row - b * NN;
                            float nm = (n < nlen[b]) ? 1.f : 0.f;
                            size_t idx = (size_t)row * 512 + col;
                            float att = nm / (1.f + expf(-(x + bias[col])));
                            float u = bf2f(Ab[idx]);
                            float l = lastf[idx];
                            float o = att * tanhf(u) + (1.f - att) * l;
                            Cf[idx] = o;  Cb[idx] = f2bf(o);
                        }
                    }
                }
            }
        }
    }
}

// All 5 weight transposes in ONE dispatch (z selects weight). fp32 [K][N]
// -> bf16 [N][K].
__global__ __launch_bounds__(256)
void wtrans_all(const float* __restrict__ W0, const float* __restrict__ W1,
                const float* __restrict__ W2, const float* __restrict__ W3,
                const float* __restrict__ W4,
                short* __restrict__ O0, short* __restrict__ O1,
                short* __restrict__ O2, short* __restrict__ O3,
                short* __restrict__ O4)
{
    const int z = blockIdx.z;
    int K, N; const float* W; short* O;
    if      (z == 0) { K = 3072; N = 512; W = W0; O = O0; }
    else if (z == 1) { K = 3072; N = 512; W = W1; O = O1; }
    else if (z == 2) { K = 512;  N = 512; W = W2; O = O2; }
    else if (z == 3) { K = 1024; N = 512; W = W3; O = O3; }
    else             { K = 2048; N = 128; W = W4; O = O4; }
    int n0 = blockIdx.x * 32, k0 = blockIdx.y * 32;
    if (n0 >= N || k0 >= K) return;
    __shared__ float tile[32][33];
    int tx = threadIdx.x, ty = threadIdx.y;
    for (int i = ty; i < 32; i += 8)
        tile[i][tx] = W[(size_t)(k0 + i) * N + n0 + tx];
    __syncthreads();
    for (int i = ty; i < 32; i += 8)
        O[(size_t)(n0 + i) * K + k0 + tx] = f2bf(tile[tx][i]);
}

// adjsumI bf16 [16][512][512] = sum_r adj + I, zero-padded (bf16 exact: 0..4)
__global__ __launch_bounds__(256)
void adjsum_conv(const float* __restrict__ adj, short* __restrict__ out)
{
    int i = blockIdx.x * 256 + threadIdx.x;
    int b = i >> 18;
    int rem = i & (512 * 512 - 1);
    int n = rem >> 9, m = rem & 511;
    float v = 0.f;
    if (n < NN && m < NN) {
        const float* base = adj + (((size_t)b * RR) * NN + n) * NN + m;
        v = base[0] + base[(size_t)NN * NN] + base[2 * (size_t)NN * NN];
        if (n == m) v += 1.f;
    }
    out[i] = f2bf(v);
}

// ---------------------------------------------------------------------------
// sim + softmax + n2q + simmax: block = 256 threads, 16 nodes per block.
// ---------------------------------------------------------------------------
__global__ __launch_bounds__(256)
void sim_n2q2(const float* __restrict__ last_f, const short* __restrict__ query_b,
              const float* __restrict__ Wa, short* __restrict__ n2q_b,
              float* __restrict__ simmax)
{
    __shared__ short qL[32 * 520];   // rows 0..24 valid
    __shared__ short cfL[16 * 520];
    __shared__ float pL[16 * 32];

    const int t = threadIdx.x;
    const int b = blockIdx.y;
    const int nbase = blockIdx.x * 16;
    const int nl = t >> 4, c = t & 15;
    const int n = nbase + nl;
    const bool valid = (n < NN);
    const int rowg = b * NN + (valid ? n : NN - 1);

    for (int i = t; i < 1600; i += 256) {
        int q = i >> 6, dc = i & 63;
        s16x8 v = *(const s16x8*)(query_b + ((size_t)b * QQ + q) * 512 + dc * 8);
        *(s16x8*)&qL[q * 520 + dc * 8] = v;
    }

    float apart = 0.f;
    {
        const float* lr = last_f + (size_t)rowg * 512 + c * 32;
        s16x8 pk[4];
        #pragma unroll
        for (int j = 0; j < 32; ++j) {
            int d = c * 32 + j;
            float lv = lr[j];
            apart += lv * Wa[d];
            pk[j >> 3][j & 7] = f2bf(Wa[512 + d] + lv * Wa[1024 + d]);
        }
        #pragma unroll
        for (int jj = 0; jj < 4; ++jj)
            *(s16x8*)&cfL[nl * 520 + c * 32 + jj * 8] = pk[jj];
        #pragma unroll
        for (int o = 1; o <= 8; o <<= 1) apart += __shfl_xor(apart, o, 64);
    }
    __syncthreads();

    float sum1 = 0.f, sum2 = 0.f;
    const bool q2v = (c < 9);
    #pragma unroll 8
    for (int dc = 0; dc < 64; ++dc) {
        s16x8 cf8 = *(const s16x8*)&cfL[nl * 520 + dc * 8];
        s16x8 qa  = *(const s16x8*)&qL[c * 520 + dc * 8];
        s16x8 qb2 = *(const s16x8*)&qL[(c + 16) * 520 + dc * 8];
        #pragma unroll
        for (int e = 0; e < 8; ++e) {
            float cf = bf2f(cf8[e]);
            sum1 += cf * bf2f(qa[e]);
            sum2 += cf * bf2f(qb2[e]);
        }
    }
    float s1 = apart + sum1;
    float s2 = q2v ? (apart + sum2) : -INFINITY;
    float m = fmaxf(s1, s2);
    #pragma unroll
    for (int o = 1; o <= 8; o <<= 1) m = fmaxf(m, __shfl_xor(m, o, 64));
    float e1 = expf(s1 - m);
    float e2 = q2v ? expf(s2 - m) : 0.f;
    float den = e1 + e2;
    #pragma unroll
    for (int o = 1; o <= 8; o <<= 1) den += __shfl_xor(den, o, 64);
    float inv = 1.f / den;
    pL[nl * 32 + c]      = e1 * inv;
    pL[nl * 32 + c + 16] = e2 * inv;
    if (c == 0 && valid) simmax[b * NN + n] = m;
    __syncthreads();

    float accv[4][8];
    #pragma unroll
    for (int jj = 0; jj < 4; ++jj)
        #pragma unroll
        for (int e = 0; e < 8; ++e) accv[jj][e] = 0.f;
    for (int q = 0; q < QQ; ++q) {
        float p = pL[nl * 32 + q];
        #pragma unroll
        for (int jj = 0; jj < 4; ++jj) {
            s16x8 q8 = *(const s16x8*)&qL[q * 520 + (jj * 16 + c) * 8];
            #pragma unroll
            for (int e = 0; e < 8; ++e) accv[jj][e] += p * bf2f(q8[e]);
        }
    }
    if (valid) {
        #pragma unroll
        for (int jj = 0; jj < 4; ++jj) {
            s16x8 o8;
            #pragma unroll
            for (int e = 0; e < 8; ++e) o8[e] = f2bf(accv[jj][e]);
            *(s16x8*)(n2q_b + ((size_t)b * NN + n) * 512 + jj * 128 + c * 8) = o8;
        }
    }
}

// b_att softmax over n + q2n; grid (8 d-blocks, 16 b)
__global__ __launch_bounds__(256)
void batt_q2n2(const float* __restrict__ simmax, const short* __restrict__ nc_b,
               short* __restrict__ q2n_b)
{
    __shared__ float pL[NN];
    __shared__ float red[4];
    __shared__ float part[4][64];
    const int b = blockIdx.y, d0 = blockIdx.x * 64;
    const int t = threadIdx.x, wv = t >> 6, lane = t & 63;
    const float* sm = simmax + (size_t)b * NN;

    float m = -INFINITY;
    for (int n = t; n < NN; n += 256) m = fmaxf(m, sm[n]);
    #pragma unroll
    for (int o = 32; o >= 1; o >>= 1) m = fmaxf(m, __shfl_xor(m, o, 64));
    if (lane == 0) red[wv] = m;
    __syncthreads();
    float M4 = fmaxf(fmaxf(red[0], red[1]), fmaxf(red[2], red[3]));
    __syncthreads();

    float den = 0.f;
    for (int n = t; n < NN; n += 256) { float e = expf(sm[n] - M4); pL[n] = e; den += e; }
    #pragma unroll
    for (int o = 32; o >= 1; o >>= 1) den += __shfl_xor(den, o, 64);
    if (lane == 0) red[wv] = den;
    __syncthreads();
    float invD = 1.f / (red[0] + red[1] + red[2] + red[3]);

    int d = d0 + (t & 63);
    int pi = t >> 6;
    float acc = 0.f;
    for (int n = pi * 125; n < pi * 125 + 125; ++n)
        acc += pL[n] * bf2f(nc_b[((size_t)b * NN + n) * 512 + d]);
    part[pi][t & 63] = acc;
    __syncthreads();
    if (t < 64)
        q2n_b[(size_t)b * 512 + d0 + t] =
            f2bf((part[0][t] + part[1][t] + part[2][t] + part[3][t]) * invD);
}

__global__ __launch_bounds__(64)
void out_kernel(const int* __restrict__ mask, const float* __restrict__ raw,
                float* __restrict__ out)
{
    int bc = blockIdx.x;
    int b  = bc / CC;
    int lane = threadIdx.x;
    const int*   mrow = mask + (size_t)bc * NN;
    const float* rrow = raw  + (size_t)b * NN;
    float mx = -INFINITY;
    for (int n = lane; n < NN; n += 64) {
        float v = (float)mrow[n] * rrow[n];
        v = (v == 0.f) ? -INFINITY : v;
        mx = fmaxf(mx, v);
    }
    #pragma unroll
    for (int o = 32; o >= 1; o >>= 1) mx = fmaxf(mx, __shfl_xor(mx, o, 64));
    if (lane == 0) out[bc] = mx;
}

extern "C" void kernel_launch(void* const* d_in, const int* in_sizes, int n_in,
                              void* d_out, int out_size, void* d_ws, size_t ws_size,
                              hipStream_t stream)
{
    const float* nodes_elmo = (const float*)d_in[0];
    const float* query_elmo = (const float*)d_in[1];
    const float* adj        = (const float*)d_in[2];
    const int*   mask       = (const int*)  d_in[3];
    const int*   nlen       = (const int*)  d_in[4];
    const float* Wq  = (const float*)d_in[6];
    const float* bq  = (const float*)d_in[7];
    const float* Wn  = (const float*)d_in[8];
    const float* bn  = (const float*)d_in[9];
    const float* Wh  = (const float*)d_in[10];
    const float* bh  = (const float*)d_in[11];
    const float* Wc  = (const float*)d_in[12];
    const float* bc  = (const float*)d_in[13];
    const float* Wa  = (const float*)d_in[14];
    const float* Wo1 = (const float*)d_in[15];
    const float* bo1 = (const float*)d_in[16];
    const float* Wo2 = (const float*)d_in[17];
    const float* bo2 = (const float*)d_in[18];
    float* out = (float*)d_out;

    char* p = (char*)d_ws;
    auto carveF = [&](size_t n) { float* r = (float*)p; p += n * 4; return r; };
    auto carveS = [&](size_t n) { short* r = (short*)p; p += n * 2; return r; };

    float* last_f0   = carveF((size_t)MROWS * 512);
    float* last_f1   = carveF((size_t)MROWS * 512);
    float* simmax    = carveF(MROWS);
    float* raw       = carveF(MROWS + 64);
    short* query_b   = carveS((size_t)400 * 512);
    short* nc_b      = carveS((size_t)MROWS * 512);
    short* last_b0   = carveS((size_t)MROWS * 512);
    short* last_b1   = carveS((size_t)MROWS * 512);
    short* hT_b      = carveS((size_t)BB * 512 * 512);
    short* update_b  = carveS((size_t)MROWS * 512);
    short* n2q_b     = carveS((size_t)MROWS * 512);
    short* adjsum_b  = carveS((size_t)BB * 512 * 512);
    short* q2n_b     = carveS((size_t)BB * 512);
    short* WqT       = carveS((size_t)512 * 3072);
    short* WnT       = carveS((size_t)512 * 3072);
    short* WhT       = carveS((size_t)512 * 512);
    short* WcT       = carveS((size_t)512 * 1024);
    short* Wo1T      = carveS((size_t)128 * 2048);

    // all weight transposes in one dispatch
    wtrans_all<<<dim3(16, 96, 5), dim3(32, 8), 0, stream>>>(
        Wq, Wn, Wh, Wc, Wo1, WqT, WnT, WhT, WcT, Wo1T);

    adjsum_conv<<<(BB * 512 * 512) / 256, 256, 0, stream>>>(adj, adjsum_b);

    // query = qelmo @ Wq + bq (fp32 in, bf16 out)
    gemm_mfma<0, 3072, 64, 0><<<dim3(4, 7), 256, 0, stream>>>(
        query_elmo, nullptr, nullptr, WqT, bq, nullptr, query_b, nullptr,
        nullptr, nullptr, nullptr, nullptr, nullptr, nullptr, nullptr, 399);

    // nc = tanh(nodes@Wn+bn); last0 = nc*nmask  (XCD panel swizzle, 63->64 pad)
    gemm_mfma<1, 3072, 128, 1><<<256, 256, 0, stream>>>(
        nodes_elmo, nullptr, nullptr, WnT, bn, last_f0, nc_b, last_b0,
        nullptr, nullptr, nullptr, nullptr, nullptr, nullptr, nlen, MROWS - 1);

    float* lf_cur = last_f0; float* lf_nxt = last_f1;
    short* lb_cur = last_b0; short* lb_nxt = last_b1;
    for (int hop = 0; hop < HOPS; ++hop) {
        // hT = ((last @ Wh + bh)*nmask)^T per b  (panel swizzle, 125->128 pad)
        gemm_mfma<2, 512, 64, 1><<<512, 256, 0, stream>>>(
            nullptr, lb_cur, nullptr, WhT, bh, nullptr, hT_b, nullptr,
            nullptr, nullptr, nullptr, nullptr, nullptr, nullptr, nlen, MROWS - 1);

        // update = (adjsum+I) @ h  (z -> XCD z%8; A[z]+B[z] = 1MB fits L2)
        gemm_mfma<3, 512, 128, 2><<<256, 256, 0, stream>>>(
            nullptr, adjsum_b, nullptr, hT_b, nullptr, nullptr, update_b,
            nullptr, nullptr, nullptr, nullptr, nullptr, nullptr, nullptr,
            nullptr, 511);

        // gate (panel swizzle)
        gemm_mfma<4, 1024, 64, 1><<<512, 256, 0, stream>>>(
            nullptr, update_b, lb_cur, WcT, bc, lf_nxt, lb_nxt, nullptr,
            lf_cur, nullptr, nullptr, nullptr, nullptr, nullptr, nlen, MROWS - 1);

        float* tf = lf_cur; lf_cur = lf_nxt; lf_nxt = tf;
        short* ts = lb_cur; lb_cur = lb_nxt; lb_nxt = ts;
    }

    sim_n2q2<<<dim3(32, 16), 256, 0, stream>>>(lf_cur, query_b, Wa, n2q_b, simmax);
    batt_q2n2<<<dim3(8, 16), 256, 0, stream>>>(simmax, nc_b, q2n_b);

    // hidden=tanh(g@Wo1+bo1); raw fused  (BM=32 -> 250 blocks)
    gemm_mfma<5, 2048, 32, 0><<<dim3(1, 250), 256, 0, stream>>>(
        nullptr, nc_b, nullptr, Wo1T, bo1, nullptr, nullptr, nullptr,
        nullptr, n2q_b, q2n_b, Wo2, bo2, raw, nullptr, MROWS - 1);

    out_kernel<<<BB * CC, 64, 0, stream>>>(mask, raw, out);
}